// Round 5
// baseline (1055.006 us; speedup 1.0000x reference)
//
#include <hip/hip_runtime.h>
#include <math.h>

typedef long long i64;
typedef unsigned short u16;
typedef unsigned int u32;

#define HW 16384
#define DIM 192
#define NHEADS 4
#define CH 48
#define OQKV 576
#define HID 510
#define H2 1020
#define NB 4
#define NSPLIT 64

typedef __attribute__((ext_vector_type(8))) short short8v;
typedef __attribute__((ext_vector_type(4))) float float4v;

__device__ __forceinline__ u16 f2bf(float f) {
  union { float f; u32 u; } v; v.f = f;
  u32 r = v.u + 0x7FFF + ((v.u >> 16) & 1);
  return (u16)(r >> 16);
}
__device__ __forceinline__ float bflo(u32 w) {
  union { u32 u; float f; } v; v.u = w << 16; return v.f;
}
__device__ __forceinline__ float bfhi(u32 w) {
  union { u32 u; float f; } v; v.u = w & 0xFFFF0000u; return v.f;
}
__device__ __forceinline__ float bf1(u16 h) {
  union { u32 u; float f; } v; v.u = ((u32)h) << 16; return v.f;
}
__device__ __forceinline__ u32 pk(float a, float b) {
  return (u32)f2bf(a) | ((u32)f2bf(b) << 16);
}
__device__ __forceinline__ float gelu_f(float x) {
  float y = 0.7978845608f * (x + 0.044715f * x * x * x);
  float ay = fabsf(y);
  float e = __expf(-2.f * ay);
  float t = (1.f - e) / (1.f + e);
  t = (y < 0.f) ? -t : t;
  return 0.5f * x * (1.f + t);
}

#define GLL16(gp, lp) __builtin_amdgcn_global_load_lds( \
    (const __attribute__((address_space(1))) u32*)(gp), \
    (__attribute__((address_space(3))) u32*)(lp), 16, 0, 0)

// ---------------- LayerNorm over channels -> bf16 pixel-major [N,192] --------
// 32 px/block; LDS transpose so global writes are fully contiguous per block.
__global__ __launch_bounds__(256) void ln_kernel(const float* __restrict__ x,
    const float* __restrict__ w, const float* __restrict__ b, u16* __restrict__ yT) {
  __shared__ float st[32][193];
  __shared__ float red[2][8][32];
  __shared__ float murs[2][32];
  const float* xb = x + (i64)blockIdx.y * DIM * HW;
  u16* yb = yT + (i64)blockIdx.y * (i64)HW * DIM;
  int tid = threadIdx.x;
  int g = tid >> 5, p = tid & 31;
  int pix0 = blockIdx.x * 32;
  float s = 0.f, ss = 0.f;
  #pragma unroll
  for (int i = 0; i < 24; ++i) {
    float t = xb[(i64)(g * 24 + i) * HW + pix0 + p];
    st[p][g * 24 + i] = t; s += t; ss += t * t;
  }
  red[0][g][p] = s; red[1][g][p] = ss;
  __syncthreads();
  if (tid < 32) {
    float S = 0.f, SS = 0.f;
    #pragma unroll
    for (int gg = 0; gg < 8; ++gg) { S += red[0][gg][tid]; SS += red[1][gg][tid]; }
    float mu = S * (1.f / DIM);
    float var = SS * (1.f / DIM) - mu * mu;
    murs[0][tid] = mu;
    murs[1][tid] = rsqrtf(var + 1e-5f);
  }
  __syncthreads();
  int px = tid >> 3, c0 = (tid & 7) * 24;
  float mu = murs[0][px], rs = murs[1][px];
  u16 ob[24];
  #pragma unroll
  for (int i = 0; i < 24; ++i) {
    ob[i] = f2bf((st[px][c0 + i] - mu) * rs * w[c0 + i] + b[c0 + i]);
  }
  u16* yp = yb + (i64)(pix0 + px) * DIM + c0;
  #pragma unroll
  for (int j = 0; j < 3; ++j) *(uint4*)(yp + j * 8) = *(const uint4*)&ob[j * 8];
}

// ---------------- all weights fp32 -> bf16 zero-padded, one launch -----------
__global__ __launch_bounds__(256) void wconv_all(const float* __restrict__ qkv_w,
    const float* __restrict__ proj_w, const float* __restrict__ pin_w,
    const float* __restrict__ pout_w, u16* __restrict__ Wq, u16* __restrict__ Wpj,
    u16* __restrict__ Wpi, u16* __restrict__ Wpo) {
  int idx = blockIdx.x * 256 + threadIdx.x;
  const float* src; u16* dst; int O, C, Kpad;
  if (idx < 122880)      { src = qkv_w;  dst = Wq;  O = OQKV; C = 192; Kpad = 192; }
  else if (idx < 172032) { idx -= 122880; src = proj_w; dst = Wpj; O = 192;  C = 192; Kpad = 192; }
  else if (idx < 368640) { idx -= 172032; src = pin_w;  dst = Wpi; O = H2;   C = 192; Kpad = 192; }
  else if (idx < 499712) { idx -= 368640; src = pout_w; dst = Wpo; O = 192;  C = HID; Kpad = 512; }
  else return;
  int r = idx / Kpad, c = idx - r * Kpad;
  dst[idx] = f2bf((r < O && c < C) ? src[(i64)r * C + c] : 0.f);
}

// ---------------- bf16 MFMA GEMM: Out[o,n] = bias[o] + sum_k A[o,k]*B[n,k] ----
__global__ __launch_bounds__(256) void gemm_bf16(const u16* __restrict__ A,
    const float* __restrict__ bias, const u16* __restrict__ B,
    const float* __restrict__ Res, float* __restrict__ Out,
    u16* __restrict__ OutB, int O, int K) {
  __shared__ __align__(16) u16 lds[2 * 128 * 64];
  int tid = threadIdx.x;
  int lane = tid & 63, wave = tid >> 6;
  int wm = (wave >> 1) * 64, wn = (wave & 1) * 64;
  int obase = blockIdx.y * 128, nbase = blockIdx.x * 128;
  float4v acc[4][4];
  #pragma unroll
  for (int m = 0; m < 4; ++m)
    #pragma unroll
    for (int n = 0; n < 4; ++n) acc[m][n] = (float4v){0.f, 0.f, 0.f, 0.f};

  const u16* Abase = A + (i64)obase * K;
  const u16* Bbase = B + (i64)nbase * K;
  char* ldsA = (char*)&lds[0];
  char* ldsB = (char*)&lds[8192];
  int srow = wave * 8 + (lane >> 3);
  int sj = lane & 7;

  for (int k0 = 0; k0 < K; k0 += 64) {
    #pragma unroll
    for (int iss = 0; iss < 4; ++iss) {
      int r = iss * 32 + srow;
      int kb = sj ^ (r & 7);
      GLL16(Abase + (i64)r * K + k0 + kb * 8, ldsA + iss * 4096 + wave * 1024);
      GLL16(Bbase + (i64)r * K + k0 + kb * 8, ldsB + iss * 4096 + wave * 1024);
    }
    __syncthreads();
    #pragma unroll
    for (int kk = 0; kk < 2; ++kk) {
      short8v af[4], bfr[4];
      #pragma unroll
      for (int m = 0; m < 4; ++m) {
        int r = wm + m * 16 + (lane & 15);
        int kb = kk * 4 + (lane >> 4);
        af[m] = *(const short8v*)(ldsA + r * 128 + ((kb ^ (r & 7)) << 4));
      }
      #pragma unroll
      for (int n = 0; n < 4; ++n) {
        int r = wn + n * 16 + (lane & 15);
        int kb = kk * 4 + (lane >> 4);
        bfr[n] = *(const short8v*)(ldsB + r * 128 + ((kb ^ (r & 7)) << 4));
      }
      #pragma unroll
      for (int m = 0; m < 4; ++m)
        #pragma unroll
        for (int n = 0; n < 4; ++n)
          acc[m][n] = __builtin_amdgcn_mfma_f32_16x16x32_bf16(af[m], bfr[n], acc[m][n], 0, 0, 0);
    }
    __syncthreads();
  }

  int rowq = lane >> 4, coln = lane & 15;
  #pragma unroll
  for (int m = 0; m < 4; ++m) {
    #pragma unroll
    for (int reg = 0; reg < 4; ++reg) {
      int o = obase + wm + m * 16 + rowq * 4 + reg;
      if (o >= O) continue;
      float bv = bias[o];
      #pragma unroll
      for (int n = 0; n < 4; ++n) {
        int nn = nbase + wn + n * 16 + coln;
        float v = acc[m][n][reg] + bv;
        if (OutB) {
          OutB[(i64)o * HW + nn] = f2bf(v);
        } else {
          if (Res) v += Res[(i64)o * HW + nn];
          Out[(i64)o * HW + nn] = v;
        }
      }
    }
  }
}

// ---------------- depthwise 3x3, bf16 in [C,HW] -> bf16 out [C,HW] -----------
__global__ __launch_bounds__(256) void dwconv_bf16(const u16* __restrict__ in,
    const float* __restrict__ w9, const float* __restrict__ bs,
    u16* __restrict__ out) {
  int q = threadIdx.x & 31;
  int grp = threadIdx.x >> 5;
  int y = blockIdx.y;
  int c0 = blockIdx.x * 64 + grp * 8;
  int xb = q * 4;
  #pragma unroll
  for (int i = 0; i < 8; ++i) {
    int c = c0 + i;
    const float* wp = w9 + c * 9;
    float bv = bs[c];
    float a0 = bv, a1 = bv, a2 = bv, a3 = bv;
    const u16* chan = in + (i64)c * HW;
    #pragma unroll
    for (int dy = -1; dy <= 1; ++dy) {
      int yy = y + dy;
      if (yy < 0 || yy >= 128) continue;
      uint4 raw = *(const uint4*)(chan + yy * 128 + xb - 2);
      float f1 = bfhi(raw.x);
      float f2 = bflo(raw.y), f3 = bfhi(raw.y);
      float f4 = bflo(raw.z), f5 = bfhi(raw.z);
      float f6 = bflo(raw.w);
      if (q == 0) f1 = 0.f;
      if (q == 31) f6 = 0.f;
      float wa = wp[(dy + 1) * 3 + 0], wb = wp[(dy + 1) * 3 + 1], wc = wp[(dy + 1) * 3 + 2];
      a0 += wa * f1 + wb * f2 + wc * f3;
      a1 += wa * f2 + wb * f3 + wc * f4;
      a2 += wa * f3 + wb * f4 + wc * f5;
      a3 += wa * f4 + wb * f5 + wc * f6;
    }
    ushort4 o;
    o.x = f2bf(a0); o.y = f2bf(a1); o.z = f2bf(a2); o.w = f2bf(a3);
    *(ushort4*)(out + (i64)c * HW + y * 128 + xb) = o;
  }
}

// ---------------- q @ k^T split-K partials + sq-norm partials (bf16 in) ------
__global__ __launch_bounds__(256) void attn_qk_kernel(const u16* __restrict__ qkv,
    float* __restrict__ part, float* __restrict__ partN) {
  __shared__ float qs[48][128];
  __shared__ float ks[48][128];
  int h = blockIdx.x, sp = blockIdx.y;
  int n0 = sp * (HW / NSPLIT);
  const u16* qb = qkv + (i64)(h * CH) * HW + n0;
  const u16* kb = qkv + (i64)(DIM + h * CH) * HW + n0;
  int tid = threadIdx.x;
  int c0 = (tid >> 4) * 3, d0 = (tid & 15) * 3;
  bool isq = (tid & 15) == 0;
  bool isk = (tid >> 4) == 0;
  float acc[3][3] = {};
  float qn[3] = {}, kn[3] = {};
  for (int nn = 0; nn < 256; nn += 128) {
    for (int l = tid; l < 48 * 16; l += 256) {
      int r = l >> 4, j = (l & 15) * 8;
      uint4 rq = *(const uint4*)(qb + (i64)r * HW + nn + j);
      uint4 rk = *(const uint4*)(kb + (i64)r * HW + nn + j);
      qs[r][j + 0] = bflo(rq.x); qs[r][j + 1] = bfhi(rq.x);
      qs[r][j + 2] = bflo(rq.y); qs[r][j + 3] = bfhi(rq.y);
      qs[r][j + 4] = bflo(rq.z); qs[r][j + 5] = bfhi(rq.z);
      qs[r][j + 6] = bflo(rq.w); qs[r][j + 7] = bfhi(rq.w);
      ks[r][j + 0] = bflo(rk.x); ks[r][j + 1] = bfhi(rk.x);
      ks[r][j + 2] = bflo(rk.y); ks[r][j + 3] = bfhi(rk.y);
      ks[r][j + 4] = bflo(rk.z); ks[r][j + 5] = bfhi(rk.z);
      ks[r][j + 6] = bflo(rk.w); ks[r][j + 7] = bfhi(rk.w);
    }
    __syncthreads();
    #pragma unroll 2
    for (int j = 0; j < 128; j += 4) {
      float qv[3][4], kv[3][4];
      #pragma unroll
      for (int i = 0; i < 3; ++i) {
        float4 t = *(const float4*)&qs[c0 + i][j];
        qv[i][0] = t.x; qv[i][1] = t.y; qv[i][2] = t.z; qv[i][3] = t.w;
        float4 u = *(const float4*)&ks[d0 + i][j];
        kv[i][0] = u.x; kv[i][1] = u.y; kv[i][2] = u.z; kv[i][3] = u.w;
      }
      #pragma unroll
      for (int i = 0; i < 3; ++i)
        #pragma unroll
        for (int jj = 0; jj < 3; ++jj)
          #pragma unroll
          for (int e = 0; e < 4; ++e)
            acc[i][jj] += qv[i][e] * kv[jj][e];
      if (isq) {
        #pragma unroll
        for (int i = 0; i < 3; ++i)
          #pragma unroll
          for (int e = 0; e < 4; ++e) qn[i] += qv[i][e] * qv[i][e];
      }
      if (isk) {
        #pragma unroll
        for (int i = 0; i < 3; ++i)
          #pragma unroll
          for (int e = 0; e < 4; ++e) kn[i] += kv[i][e] * kv[i][e];
      }
    }
    __syncthreads();
  }
  float* pp = part + ((i64)(h * NSPLIT) + sp) * 2304;
  #pragma unroll
  for (int i = 0; i < 3; ++i)
    #pragma unroll
    for (int jj = 0; jj < 3; ++jj)
      pp[(c0 + i) * 48 + d0 + jj] = acc[i][jj];
  float* pn = partN + ((i64)(h * NSPLIT) + sp) * 96;
  if (isq) {
    #pragma unroll
    for (int i = 0; i < 3; ++i) pn[c0 + i] = qn[i];
  }
  if (isk) {
    #pragma unroll
    for (int i = 0; i < 3; ++i) pn[48 + d0 + i] = kn[i];
  }
}

// ---------------- fused norm-reduce + scale + softmax, grid = NHEADS ---------
__global__ __launch_bounds__(256) void attn_sm2(const float* __restrict__ part,
    const float* __restrict__ partN, const float* __restrict__ temp,
    float* __restrict__ attn) {
  __shared__ float inv[96];
  int h = blockIdx.x, tid = threadIdx.x;
  if (tid < 96) {
    float s = 0.f;
    for (int sp = 0; sp < NSPLIT; ++sp) s += partN[((i64)(h * NSPLIT) + sp) * 96 + tid];
    inv[tid] = 1.f / fmaxf(sqrtf(s), 1e-12f);
  }
  __syncthreads();
  int wv = tid >> 6, d = tid & 63;
  float tmp = temp[h];
  for (int c = wv; c < CH; c += 4) {
    float logit = -1e30f;
    if (d < CH) {
      float s = 0.f;
      for (int sp = 0; sp < NSPLIT; ++sp)
        s += part[((i64)(h * NSPLIT) + sp) * 2304 + c * 48 + d];
      logit = s * inv[c] * inv[48 + d] * tmp;
    }
    float m = logit;
    #pragma unroll
    for (int mask = 32; mask; mask >>= 1) m = fmaxf(m, __shfl_xor(m, mask));
    float e = (d < CH) ? expf(logit - m) : 0.f;
    float ssum = e;
    #pragma unroll
    for (int mask = 32; mask; mask >>= 1) ssum += __shfl_xor(ssum, mask);
    if (d < CH) attn[(i64)h * 2304 + c * 48 + d] = e / ssum;
  }
}

// ---------------- out = attn @ v (bf16 v); LDS-staged coalesced bf16 writes --
__global__ __launch_bounds__(256) void attn_v_kernel(const u16* __restrict__ qkv,
    const float* __restrict__ attnm, u16* __restrict__ outT) {
  __shared__ float as[CH * CH];
  __shared__ u16 st[256 * 52];      // row stride 52 u16 = 26 dwords
  int h = blockIdx.x, tile = blockIdx.y;
  int tid = threadIdx.x;
  for (int l = tid; l < CH * CH; l += 256) as[l] = attnm[(i64)h * 2304 + l];
  __syncthreads();
  int n = tile * 256 + tid;
  const u16* vb = qkv + (i64)(2 * DIM + h * CH) * HW + n;
  float vreg[CH];
  #pragma unroll
  for (int d = 0; d < CH; ++d) vreg[d] = bf1(vb[(i64)d * HW]);
  u32* strow = (u32*)st + tid * 26;
  #pragma unroll 2
  for (int c = 0; c < CH; c += 4) {
    float a0 = 0.f, a1 = 0.f, a2 = 0.f, a3 = 0.f;
    const float* r0 = &as[(c + 0) * CH];
    const float* r1 = &as[(c + 1) * CH];
    const float* r2 = &as[(c + 2) * CH];
    const float* r3 = &as[(c + 3) * CH];
    #pragma unroll
    for (int d = 0; d < CH; ++d) {
      float vv = vreg[d];
      a0 += r0[d] * vv; a1 += r1[d] * vv; a2 += r2[d] * vv; a3 += r3[d] * vv;
    }
    strow[(c >> 1) + 0] = pk(a0, a1);
    strow[(c >> 1) + 1] = pk(a2, a3);
  }
  __syncthreads();
  const uint2* sv = (const uint2*)st;  // row = 13 uint2
  u16* ob = outT + (i64)(tile * 256) * DIM + h * CH;
  #pragma unroll
  for (int k = 0; k < 12; ++k) {
    int idx = k * 256 + tid;
    int px = idx / 12, pc = idx - px * 12;
    *(uint2*)(ob + (i64)px * DIM + pc * 4) = sv[px * 13 + pc];
  }
}

// ---------------- fused FFN dw3x3 + GELU gate -> bf16 [N,512], LDS-staged ----
__global__ __launch_bounds__(256) void dwgate_bf16(const u16* __restrict__ h1,
    const float* __restrict__ w9, const float* __restrict__ bs,
    u16* __restrict__ og) {
  __shared__ u32 st[128 * 33];      // [px][32 dw of 64ch] + 1 pad dw
  int q = threadIdx.x & 31;
  int grp = threadIdx.x >> 5;
  int y = blockIdx.y;
  int c0 = blockIdx.x * 64 + grp * 8;
  int xb = q * 4;
  float res[4][8];
  #pragma unroll
  for (int i = 0; i < 8; ++i) {
    int c = c0 + i;
    bool valid = (c < HID);
    float b1 = valid ? bs[c] : 0.f;
    float b2 = valid ? bs[c + HID] : 0.f;
    float a0 = b1, a1 = b1, a2 = b1, a3 = b1;
    float g0 = b2, g1 = b2, g2 = b2, g3 = b2;
    if (valid) {
      const float* wp1 = w9 + c * 9;
      const float* wp2 = w9 + (i64)(c + HID) * 9;
      const u16* ch1 = h1 + (i64)c * HW;
      const u16* ch2 = h1 + (i64)(c + HID) * HW;
      #pragma unroll
      for (int dy = -1; dy <= 1; ++dy) {
        int yy = y + dy;
        if (yy < 0 || yy >= 128) continue;
        {
          uint4 raw = *(const uint4*)(ch1 + yy * 128 + xb - 2);
          float f1 = bfhi(raw.x);
          float f2 = bflo(raw.y), f3 = bfhi(raw.y);
          float f4 = bflo(raw.z), f5 = bfhi(raw.z);
          float f6 = bflo(raw.w);
          if (q == 0) f1 = 0.f;
          if (q == 31) f6 = 0.f;
          float wa = wp1[(dy + 1) * 3 + 0], wb = wp1[(dy + 1) * 3 + 1], wc = wp1[(dy + 1) * 3 + 2];
          a0 += wa * f1 + wb * f2 + wc * f3;
          a1 += wa * f2 + wb * f3 + wc * f4;
          a2 += wa * f3 + wb * f4 + wc * f5;
          a3 += wa * f4 + wb * f5 + wc * f6;
        }
        {
          uint4 raw = *(const uint4*)(ch2 + yy * 128 + xb - 2);
          float f1 = bfhi(raw.x);
          float f2 = bflo(raw.y), f3 = bfhi(raw.y);
          float f4 = bflo(raw.z), f5 = bfhi(raw.z);
          float f6 = bflo(raw.w);
          if (q == 0) f1 = 0.f;
          if (q == 31) f6 = 0.f;
          float wa = wp2[(dy + 1) * 3 + 0], wb = wp2[(dy + 1) * 3 + 1], wc = wp2[(dy + 1) * 3 + 2];
          g0 += wa * f1 + wb * f2 + wc * f3;
          g1 += wa * f2 + wb * f3 + wc * f4;
          g2 += wa * f3 + wb * f4 + wc * f5;
          g3 += wa * f4 + wb * f5 + wc * f6;
        }
      }
    }
    res[0][i] = valid ? gelu_f(a0) * g0 : 0.f;
    res[1][i] = valid ? gelu_f(a1) * g1 : 0.f;
    res[2][i] = valid ? gelu_f(a2) * g2 : 0.f;
    res[3][i] = valid ? gelu_f(a3) * g3 : 0.f;
  }
  #pragma unroll
  for (int j = 0; j < 4; ++j) {
    int px = xb + j;
    u32* row = st + px * 33 + grp * 4;
    row[0] = pk(res[j][0], res[j][1]);
    row[1] = pk(res[j][2], res[j][3]);
    row[2] = pk(res[j][4], res[j][5]);
    row[3] = pk(res[j][6], res[j][7]);
  }
  __syncthreads();
  u32* og32 = (u32*)og;
  int tid = threadIdx.x;
  #pragma unroll
  for (int k = 0; k < 16; ++k) {
    int idx = k * 256 + tid;
    int px = idx >> 5, dwi = idx & 31;
    og32[(i64)(y * 128 + px) * 256 + (c0 >> 1) - (grp * 4) + ((grp * 4 + 0) & 0) + (blockIdx.x * 32) * 0 + dwi + (c0 - grp * 8) / 2 * 0 + (blockIdx.x * 64 / 2) - (c0 >> 1) + dwi * 0] = st[px * 33 + dwi];
  }
}

extern "C" void kernel_launch(void* const* d_in, const int* in_sizes, int n_in,
                              void* d_out, int out_size, void* d_ws, size_t ws_size,
                              hipStream_t stream) {
  const float* x        = (const float*)d_in[0];
  const float* ln1_w    = (const float*)d_in[1];
  const float* ln1_b    = (const float*)d_in[2];
  const float* qkv_w    = (const float*)d_in[3];
  const float* qkv_b    = (const float*)d_in[4];
  const float* qkv_dw_w = (const float*)d_in[5];
  const float* qkv_dw_b = (const float*)d_in[6];
  const float* temp     = (const float*)d_in[7];
  const float* proj_w   = (const float*)d_in[8];
  const float* proj_b   = (const float*)d_in[9];
  const float* ln2_w    = (const float*)d_in[10];
  const float* ln2_b    = (const float*)d_in[11];
  const float* pin_w    = (const float*)d_in[12];
  const float* pin_b    = (const float*)d_in[13];
  const float* dw_w     = (const float*)d_in[14];
  const float* dw_b     = (const float*)d_in[15];
  const float* pout_w   = (const float*)d_in[16];
  const float* pout_b   = (const float*)d_in[17];
  float* out = (float*)d_out;
  char* ws = (char*)d_ws;

  u16* Wq   = (u16*)ws;                        // 640*192
  u16* Wpj  = Wq + 640 * 192;                  // 256*192
  u16* Wpi  = Wpj + 256 * 192;                 // 1024*192
  u16* Wpo  = Wpi + 1024 * 192;                // 256*512
  float* attnm = (float*)(Wpo + 256 * 512);    // 9216
  float* part  = attnm + 9216;                 // 589824
  float* partN = part + 589824;                // 24576
  u16* yT   = (u16*)(partN + 24576);           // NB * HW * 192
  u16* bufA = yT + (i64)NB * HW * DIM;         // 1020*HW bf16 (qkv1/h1/attnoutT)
  u16* bufQ = bufA + (i64)H2 * HW;             // 576*HW bf16 (qkv post-dw / gatedT)
  u16* attnoutT = bufA;
  u16* gatedT = bufQ;
  size_t need = (size_t)((char*)(bufQ + (i64)OQKV * HW) - ws);
  if (ws_size < need) return;

  wconv_all<<<(499712 + 255) / 256, 256, 0, stream>>>(qkv_w, proj_w, pin_w, pout_w,
                                                      Wq, Wpj, Wpi, Wpo);
  // LN1 for all batches at once
  ln_kernel<<<dim3(HW / 32, NB), 256, 0, stream>>>(x, ln1_w, ln1_b, yT);

  for (int b = 0; b < NB; ++b) {
    const float* xb = x + (i64)b * DIM * HW;
    float* outb = out + (i64)b * DIM * HW;
    u16* yTb = yT + (i64)b * HW * DIM;

    // ---- attention branch ----
    gemm_bf16<<<dim3(HW / 128, 640 / 128), 256, 0, stream>>>(Wq, qkv_b, yTb, nullptr, nullptr, bufA, OQKV, DIM);
    dwconv_bf16<<<dim3(OQKV / 64, 128), 256, 0, stream>>>(bufA, qkv_dw_w, qkv_dw_b, bufQ);
    attn_qk_kernel<<<dim3(NHEADS, NSPLIT), 256, 0, stream>>>(bufQ, part, partN);
    attn_sm2<<<NHEADS, 256, 0, stream>>>(part, partN, temp, attnm);
    attn_v_kernel<<<dim3(NHEADS, HW / 256), 256, 0, stream>>>(bufQ, attnm, attnoutT);
    gemm_bf16<<<dim3(HW / 128, 256 / 128), 256, 0, stream>>>(Wpj, proj_b, attnoutT, xb, outb, nullptr, DIM, DIM);

    // ---- FFN branch ----
    ln_kernel<<<dim3(HW / 32, 1), 256, 0, stream>>>(outb, ln2_w, ln2_b, yTb);
    gemm_bf16<<<dim3(HW / 128, 1024 / 128), 256, 0, stream>>>(Wpi, pin_b, yTb, nullptr, nullptr, bufA, H2, DIM);
    dwgate_bf16<<<dim3(8, 128), 256, 0, stream>>>(bufA, dw_w, dw_b, gatedT);
    gemm_bf16<<<dim3(HW / 128, 256 / 128), 256, 0, stream>>>(Wpo, pout_b, gatedT, outb, outb, nullptr, DIM, 512);
  }
}

// Round 6
// 787.455 us; speedup vs baseline: 1.3398x; 1.3398x over previous
//
#include <hip/hip_runtime.h>
#include <math.h>

typedef long long i64;
typedef unsigned short u16;
typedef unsigned int u32;

#define HW 16384
#define DIM 192
#define NHEADS 4
#define CH 48
#define OQKV 576
#define HID 510
#define H2 1020
#define NB 4
#define NSPLIT 64

typedef __attribute__((ext_vector_type(8))) short short8v;
typedef __attribute__((ext_vector_type(4))) float float4v;

__device__ __forceinline__ u16 f2bf(float f) {
  union { float f; u32 u; } v; v.f = f;
  u32 r = v.u + 0x7FFF + ((v.u >> 16) & 1);
  return (u16)(r >> 16);
}
__device__ __forceinline__ float bflo(u32 w) {
  union { u32 u; float f; } v; v.u = w << 16; return v.f;
}
__device__ __forceinline__ float bfhi(u32 w) {
  union { u32 u; float f; } v; v.u = w & 0xFFFF0000u; return v.f;
}
__device__ __forceinline__ float bf1(u16 h) {
  union { u32 u; float f; } v; v.u = ((u32)h) << 16; return v.f;
}
__device__ __forceinline__ u32 pk(float a, float b) {
  return (u32)f2bf(a) | ((u32)f2bf(b) << 16);
}
__device__ __forceinline__ float gelu_f(float x) {
  float y = 0.7978845608f * (x + 0.044715f * x * x * x);
  float ay = fabsf(y);
  float e = __expf(-2.f * ay);
  float t = (1.f - e) / (1.f + e);
  t = (y < 0.f) ? -t : t;
  return 0.5f * x * (1.f + t);
}

#define GLL16(gp, lp) __builtin_amdgcn_global_load_lds( \
    (const __attribute__((address_space(1))) u32*)(gp), \
    (__attribute__((address_space(3))) u32*)(lp), 16, 0, 0)

// ---------------- LayerNorm over channels -> bf16 pixel-major [N,192] --------
__global__ __launch_bounds__(256) void ln_kernel(const float* __restrict__ x,
    const float* __restrict__ w, const float* __restrict__ b, u16* __restrict__ yT) {
  __shared__ float st[32][193];
  __shared__ float red[2][8][32];
  __shared__ float murs[2][32];
  const float* xb = x + (i64)blockIdx.y * DIM * HW;
  u16* yb = yT + (i64)blockIdx.y * (i64)HW * DIM;
  int tid = threadIdx.x;
  int g = tid >> 5, p = tid & 31;
  int pix0 = blockIdx.x * 32;
  float s = 0.f, ss = 0.f;
  #pragma unroll
  for (int i = 0; i < 24; ++i) {
    float t = xb[(i64)(g * 24 + i) * HW + pix0 + p];
    st[p][g * 24 + i] = t; s += t; ss += t * t;
  }
  red[0][g][p] = s; red[1][g][p] = ss;
  __syncthreads();
  if (tid < 32) {
    float S = 0.f, SS = 0.f;
    #pragma unroll
    for (int gg = 0; gg < 8; ++gg) { S += red[0][gg][tid]; SS += red[1][gg][tid]; }
    float mu = S * (1.f / DIM);
    float var = SS * (1.f / DIM) - mu * mu;
    murs[0][tid] = mu;
    murs[1][tid] = rsqrtf(var + 1e-5f);
  }
  __syncthreads();
  int px = tid >> 3, c0 = (tid & 7) * 24;
  float mu = murs[0][px], rs = murs[1][px];
  u16 ob[24];
  #pragma unroll
  for (int i = 0; i < 24; ++i) {
    ob[i] = f2bf((st[px][c0 + i] - mu) * rs * w[c0 + i] + b[c0 + i]);
  }
  u16* yp = yb + (i64)(pix0 + px) * DIM + c0;
  #pragma unroll
  for (int j = 0; j < 3; ++j) *(uint4*)(yp + j * 8) = *(const uint4*)&ob[j * 8];
}

// ---------------- all weights fp32 -> bf16 zero-padded, one launch -----------
__global__ __launch_bounds__(256) void wconv_all(const float* __restrict__ qkv_w,
    const float* __restrict__ proj_w, const float* __restrict__ pin_w,
    const float* __restrict__ pout_w, u16* __restrict__ Wq, u16* __restrict__ Wpj,
    u16* __restrict__ Wpi, u16* __restrict__ Wpo) {
  int idx = blockIdx.x * 256 + threadIdx.x;
  const float* src; u16* dst; int O, C, Kpad;
  if (idx < 122880)      { src = qkv_w;  dst = Wq;  O = OQKV; C = 192; Kpad = 192; }
  else if (idx < 172032) { idx -= 122880; src = proj_w; dst = Wpj; O = 192;  C = 192; Kpad = 192; }
  else if (idx < 368640) { idx -= 172032; src = pin_w;  dst = Wpi; O = H2;   C = 192; Kpad = 192; }
  else if (idx < 499712) { idx -= 368640; src = pout_w; dst = Wpo; O = 192;  C = HID; Kpad = 512; }
  else return;
  int r = idx / Kpad, c = idx - r * Kpad;
  dst[idx] = f2bf((r < O && c < C) ? src[(i64)r * C + c] : 0.f);
}

// ---------------- bf16 MFMA GEMM: Out[o,n] = bias[o] + sum_k A[o,k]*B[n,k] ----
__global__ __launch_bounds__(256) void gemm_bf16(const u16* __restrict__ A,
    const float* __restrict__ bias, const u16* __restrict__ B,
    const float* __restrict__ Res, float* __restrict__ Out,
    u16* __restrict__ OutB, int O, int K) {
  __shared__ __align__(16) u16 lds[2 * 128 * 64];
  int tid = threadIdx.x;
  int lane = tid & 63, wave = tid >> 6;
  int wm = (wave >> 1) * 64, wn = (wave & 1) * 64;
  int obase = blockIdx.y * 128, nbase = blockIdx.x * 128;
  float4v acc[4][4];
  #pragma unroll
  for (int m = 0; m < 4; ++m)
    #pragma unroll
    for (int n = 0; n < 4; ++n) acc[m][n] = (float4v){0.f, 0.f, 0.f, 0.f};

  const u16* Abase = A + (i64)obase * K;
  const u16* Bbase = B + (i64)nbase * K;
  char* ldsA = (char*)&lds[0];
  char* ldsB = (char*)&lds[8192];
  int srow = wave * 8 + (lane >> 3);
  int sj = lane & 7;

  for (int k0 = 0; k0 < K; k0 += 64) {
    #pragma unroll
    for (int iss = 0; iss < 4; ++iss) {
      int r = iss * 32 + srow;
      int kb = sj ^ (r & 7);
      GLL16(Abase + (i64)r * K + k0 + kb * 8, ldsA + iss * 4096 + wave * 1024);
      GLL16(Bbase + (i64)r * K + k0 + kb * 8, ldsB + iss * 4096 + wave * 1024);
    }
    __syncthreads();
    #pragma unroll
    for (int kk = 0; kk < 2; ++kk) {
      short8v af[4], bfr[4];
      #pragma unroll
      for (int m = 0; m < 4; ++m) {
        int r = wm + m * 16 + (lane & 15);
        int kb = kk * 4 + (lane >> 4);
        af[m] = *(const short8v*)(ldsA + r * 128 + ((kb ^ (r & 7)) << 4));
      }
      #pragma unroll
      for (int n = 0; n < 4; ++n) {
        int r = wn + n * 16 + (lane & 15);
        int kb = kk * 4 + (lane >> 4);
        bfr[n] = *(const short8v*)(ldsB + r * 128 + ((kb ^ (r & 7)) << 4));
      }
      #pragma unroll
      for (int m = 0; m < 4; ++m)
        #pragma unroll
        for (int n = 0; n < 4; ++n)
          acc[m][n] = __builtin_amdgcn_mfma_f32_16x16x32_bf16(af[m], bfr[n], acc[m][n], 0, 0, 0);
    }
    __syncthreads();
  }

  int rowq = lane >> 4, coln = lane & 15;
  #pragma unroll
  for (int m = 0; m < 4; ++m) {
    #pragma unroll
    for (int reg = 0; reg < 4; ++reg) {
      int o = obase + wm + m * 16 + rowq * 4 + reg;
      if (o >= O) continue;
      float bv = bias[o];
      #pragma unroll
      for (int n = 0; n < 4; ++n) {
        int nn = nbase + wn + n * 16 + coln;
        float v = acc[m][n][reg] + bv;
        if (OutB) {
          OutB[(i64)o * HW + nn] = f2bf(v);
        } else {
          if (Res) v += Res[(i64)o * HW + nn];
          Out[(i64)o * HW + nn] = v;
        }
      }
    }
  }
}

// ---------------- depthwise 3x3, bf16 in [C,HW] -> bf16 out [C,HW] -----------
__global__ __launch_bounds__(256) void dwconv_bf16(const u16* __restrict__ in,
    const float* __restrict__ w9, const float* __restrict__ bs,
    u16* __restrict__ out) {
  int q = threadIdx.x & 31;
  int grp = threadIdx.x >> 5;
  int y = blockIdx.y;
  int c0 = blockIdx.x * 64 + grp * 8;
  int xb = q * 4;
  #pragma unroll
  for (int i = 0; i < 8; ++i) {
    int c = c0 + i;
    const float* wp = w9 + c * 9;
    float bv = bs[c];
    float a0 = bv, a1 = bv, a2 = bv, a3 = bv;
    const u16* chan = in + (i64)c * HW;
    #pragma unroll
    for (int dy = -1; dy <= 1; ++dy) {
      int yy = y + dy;
      if (yy < 0 || yy >= 128) continue;
      uint4 raw = *(const uint4*)(chan + yy * 128 + xb - 2);
      float f1 = bfhi(raw.x);
      float f2 = bflo(raw.y), f3 = bfhi(raw.y);
      float f4 = bflo(raw.z), f5 = bfhi(raw.z);
      float f6 = bflo(raw.w);
      if (q == 0) f1 = 0.f;
      if (q == 31) f6 = 0.f;
      float wa = wp[(dy + 1) * 3 + 0], wb = wp[(dy + 1) * 3 + 1], wc = wp[(dy + 1) * 3 + 2];
      a0 += wa * f1 + wb * f2 + wc * f3;
      a1 += wa * f2 + wb * f3 + wc * f4;
      a2 += wa * f3 + wb * f4 + wc * f5;
      a3 += wa * f4 + wb * f5 + wc * f6;
    }
    ushort4 o;
    o.x = f2bf(a0); o.y = f2bf(a1); o.z = f2bf(a2); o.w = f2bf(a3);
    *(ushort4*)(out + (i64)c * HW + y * 128 + xb) = o;
  }
}

// ---------------- q @ k^T split-K partials + sq-norm partials (bf16 in) ------
__global__ __launch_bounds__(256) void attn_qk_kernel(const u16* __restrict__ qkv,
    float* __restrict__ part, float* __restrict__ partN) {
  __shared__ float qs[48][128];
  __shared__ float ks[48][128];
  int h = blockIdx.x, sp = blockIdx.y;
  int n0 = sp * (HW / NSPLIT);
  const u16* qb = qkv + (i64)(h * CH) * HW + n0;
  const u16* kb = qkv + (i64)(DIM + h * CH) * HW + n0;
  int tid = threadIdx.x;
  int c0 = (tid >> 4) * 3, d0 = (tid & 15) * 3;
  bool isq = (tid & 15) == 0;
  bool isk = (tid >> 4) == 0;
  float acc[3][3] = {};
  float qn[3] = {}, kn[3] = {};
  for (int nn = 0; nn < 256; nn += 128) {
    for (int l = tid; l < 48 * 16; l += 256) {
      int r = l >> 4, j = (l & 15) * 8;
      uint4 rq = *(const uint4*)(qb + (i64)r * HW + nn + j);
      uint4 rk = *(const uint4*)(kb + (i64)r * HW + nn + j);
      qs[r][j + 0] = bflo(rq.x); qs[r][j + 1] = bfhi(rq.x);
      qs[r][j + 2] = bflo(rq.y); qs[r][j + 3] = bfhi(rq.y);
      qs[r][j + 4] = bflo(rq.z); qs[r][j + 5] = bfhi(rq.z);
      qs[r][j + 6] = bflo(rq.w); qs[r][j + 7] = bfhi(rq.w);
      ks[r][j + 0] = bflo(rk.x); ks[r][j + 1] = bfhi(rk.x);
      ks[r][j + 2] = bflo(rk.y); ks[r][j + 3] = bfhi(rk.y);
      ks[r][j + 4] = bflo(rk.z); ks[r][j + 5] = bfhi(rk.z);
      ks[r][j + 6] = bflo(rk.w); ks[r][j + 7] = bfhi(rk.w);
    }
    __syncthreads();
    #pragma unroll 2
    for (int j = 0; j < 128; j += 4) {
      float qv[3][4], kv[3][4];
      #pragma unroll
      for (int i = 0; i < 3; ++i) {
        float4 t = *(const float4*)&qs[c0 + i][j];
        qv[i][0] = t.x; qv[i][1] = t.y; qv[i][2] = t.z; qv[i][3] = t.w;
        float4 u = *(const float4*)&ks[d0 + i][j];
        kv[i][0] = u.x; kv[i][1] = u.y; kv[i][2] = u.z; kv[i][3] = u.w;
      }
      #pragma unroll
      for (int i = 0; i < 3; ++i)
        #pragma unroll
        for (int jj = 0; jj < 3; ++jj)
          #pragma unroll
          for (int e = 0; e < 4; ++e)
            acc[i][jj] += qv[i][e] * kv[jj][e];
      if (isq) {
        #pragma unroll
        for (int i = 0; i < 3; ++i)
          #pragma unroll
          for (int e = 0; e < 4; ++e) qn[i] += qv[i][e] * qv[i][e];
      }
      if (isk) {
        #pragma unroll
        for (int i = 0; i < 3; ++i)
          #pragma unroll
          for (int e = 0; e < 4; ++e) kn[i] += kv[i][e] * kv[i][e];
      }
    }
    __syncthreads();
  }
  float* pp = part + ((i64)(h * NSPLIT) + sp) * 2304;
  #pragma unroll
  for (int i = 0; i < 3; ++i)
    #pragma unroll
    for (int jj = 0; jj < 3; ++jj)
      pp[(c0 + i) * 48 + d0 + jj] = acc[i][jj];
  float* pn = partN + ((i64)(h * NSPLIT) + sp) * 96;
  if (isq) {
    #pragma unroll
    for (int i = 0; i < 3; ++i) pn[c0 + i] = qn[i];
  }
  if (isk) {
    #pragma unroll
    for (int i = 0; i < 3; ++i) pn[48 + d0 + i] = kn[i];
  }
}

// ---------------- reduce norm partials -> inv[4][96] -------------------------
__global__ __launch_bounds__(384) void norm_reduce(const float* __restrict__ partN,
    float* __restrict__ inv) {
  int j = threadIdx.x;           // 0..383
  int h = j / 96, r = j - h * 96;
  float s = 0.f;
  for (int sp = 0; sp < NSPLIT; ++sp) s += partN[((i64)(h * NSPLIT) + sp) * 96 + r];
  inv[h * 96 + r] = 1.f / fmaxf(sqrtf(s), 1e-12f);
}

// ---------------- reduce partials, scale, softmax; grid (NHEADS, CH) ---------
__global__ __launch_bounds__(64) void attn_sm_kernel(const float* __restrict__ part,
    const float* __restrict__ inv, const float* __restrict__ temp,
    float* __restrict__ attn) {
  int h = blockIdx.x, c = blockIdx.y;
  int d = threadIdx.x;
  float logit = -1e30f;
  if (d < CH) {
    float s = 0.f;
    for (int sp = 0; sp < NSPLIT; ++sp)
      s += part[((i64)(h * NSPLIT) + sp) * 2304 + c * 48 + d];
    logit = s * inv[h * 96 + c] * inv[h * 96 + 48 + d] * temp[h];
  }
  float m = logit;
  #pragma unroll
  for (int mask = 32; mask; mask >>= 1) m = fmaxf(m, __shfl_xor(m, mask));
  float e = (d < CH) ? expf(logit - m) : 0.f;
  float ssum = e;
  #pragma unroll
  for (int mask = 32; mask; mask >>= 1) ssum += __shfl_xor(ssum, mask);
  if (d < CH) attn[(i64)h * 2304 + c * 48 + d] = e / ssum;
}

// ---------------- out = attn @ v (bf16 v); LDS-staged coalesced bf16 writes --
__global__ __launch_bounds__(256) void attn_v_kernel(const u16* __restrict__ qkv,
    const float* __restrict__ attnm, u16* __restrict__ outT) {
  __shared__ float as[CH * CH];
  __shared__ u16 st[256 * 52];
  int h = blockIdx.x, tile = blockIdx.y;
  int tid = threadIdx.x;
  for (int l = tid; l < CH * CH; l += 256) as[l] = attnm[(i64)h * 2304 + l];
  __syncthreads();
  int n = tile * 256 + tid;
  const u16* vb = qkv + (i64)(2 * DIM + h * CH) * HW + n;
  float vreg[CH];
  #pragma unroll
  for (int d = 0; d < CH; ++d) vreg[d] = bf1(vb[(i64)d * HW]);
  u32* strow = (u32*)st + tid * 26;
  #pragma unroll 2
  for (int c = 0; c < CH; c += 4) {
    float a0 = 0.f, a1 = 0.f, a2 = 0.f, a3 = 0.f;
    const float* r0 = &as[(c + 0) * CH];
    const float* r1 = &as[(c + 1) * CH];
    const float* r2 = &as[(c + 2) * CH];
    const float* r3 = &as[(c + 3) * CH];
    #pragma unroll
    for (int d = 0; d < CH; ++d) {
      float vv = vreg[d];
      a0 += r0[d] * vv; a1 += r1[d] * vv; a2 += r2[d] * vv; a3 += r3[d] * vv;
    }
    strow[(c >> 1) + 0] = pk(a0, a1);
    strow[(c >> 1) + 1] = pk(a2, a3);
  }
  __syncthreads();
  const uint2* sv = (const uint2*)st;
  u16* ob = outT + (i64)(tile * 256) * DIM + h * CH;
  #pragma unroll
  for (int k = 0; k < 12; ++k) {
    int idx = k * 256 + tid;
    int px = idx / 12, pc = idx - px * 12;
    *(uint2*)(ob + (i64)px * DIM + pc * 4) = sv[px * 13 + pc];
  }
}

// ---------------- fused FFN dw3x3 + GELU gate -> bf16 [N,512], LDS-staged ----
__global__ __launch_bounds__(256) void dwgate_bf16(const u16* __restrict__ h1,
    const float* __restrict__ w9, const float* __restrict__ bs,
    u16* __restrict__ og) {
  __shared__ u32 st[128 * 33];
  int q = threadIdx.x & 31;
  int grp = threadIdx.x >> 5;
  int y = blockIdx.y;
  int c0 = blockIdx.x * 64 + grp * 8;
  int xb = q * 4;
  float res[4][8];
  #pragma unroll
  for (int i = 0; i < 8; ++i) {
    int c = c0 + i;
    bool valid = (c < HID);
    float b1 = valid ? bs[c] : 0.f;
    float b2 = valid ? bs[c + HID] : 0.f;
    float a0 = b1, a1 = b1, a2 = b1, a3 = b1;
    float g0 = b2, g1 = b2, g2 = b2, g3 = b2;
    if (valid) {
      const float* wp1 = w9 + c * 9;
      const float* wp2 = w9 + (i64)(c + HID) * 9;
      const u16* ch1 = h1 + (i64)c * HW;
      const u16* ch2 = h1 + (i64)(c + HID) * HW;
      #pragma unroll
      for (int dy = -1; dy <= 1; ++dy) {
        int yy = y + dy;
        if (yy < 0 || yy >= 128) continue;
        {
          uint4 raw = *(const uint4*)(ch1 + yy * 128 + xb - 2);
          float f1 = bfhi(raw.x);
          float f2 = bflo(raw.y), f3 = bfhi(raw.y);
          float f4 = bflo(raw.z), f5 = bfhi(raw.z);
          float f6 = bflo(raw.w);
          if (q == 0) f1 = 0.f;
          if (q == 31) f6 = 0.f;
          float wa = wp1[(dy + 1) * 3 + 0], wb = wp1[(dy + 1) * 3 + 1], wc = wp1[(dy + 1) * 3 + 2];
          a0 += wa * f1 + wb * f2 + wc * f3;
          a1 += wa * f2 + wb * f3 + wc * f4;
          a2 += wa * f3 + wb * f4 + wc * f5;
          a3 += wa * f4 + wb * f5 + wc * f6;
        }
        {
          uint4 raw = *(const uint4*)(ch2 + yy * 128 + xb - 2);
          float f1 = bfhi(raw.x);
          float f2 = bflo(raw.y), f3 = bfhi(raw.y);
          float f4 = bflo(raw.z), f5 = bfhi(raw.z);
          float f6 = bflo(raw.w);
          if (q == 0) f1 = 0.f;
          if (q == 31) f6 = 0.f;
          float wa = wp2[(dy + 1) * 3 + 0], wb = wp2[(dy + 1) * 3 + 1], wc = wp2[(dy + 1) * 3 + 2];
          g0 += wa * f1 + wb * f2 + wc * f3;
          g1 += wa * f2 + wb * f3 + wc * f4;
          g2 += wa * f3 + wb * f4 + wc * f5;
          g3 += wa * f4 + wb * f5 + wc * f6;
        }
      }
    }
    res[0][i] = valid ? gelu_f(a0) * g0 : 0.f;
    res[1][i] = valid ? gelu_f(a1) * g1 : 0.f;
    res[2][i] = valid ? gelu_f(a2) * g2 : 0.f;
    res[3][i] = valid ? gelu_f(a3) * g3 : 0.f;
  }
  #pragma unroll
  for (int j = 0; j < 4; ++j) {
    int px = xb + j;
    u32* row = st + px * 33 + grp * 4;
    row[0] = pk(res[j][0], res[j][1]);
    row[1] = pk(res[j][2], res[j][3]);
    row[2] = pk(res[j][4], res[j][5]);
    row[3] = pk(res[j][6], res[j][7]);
  }
  __syncthreads();
  u32* og32 = (u32*)og;
  int tid = threadIdx.x;
  #pragma unroll
  for (int k = 0; k < 16; ++k) {
    int idx = k * 256 + tid;
    int px = idx >> 5, dwi = idx & 31;
    og32[(i64)(y * 128 + px) * 256 + blockIdx.x * 32 + dwi] = st[px * 33 + dwi];
  }
}

extern "C" void kernel_launch(void* const* d_in, const int* in_sizes, int n_in,
                              void* d_out, int out_size, void* d_ws, size_t ws_size,
                              hipStream_t stream) {
  const float* x        = (const float*)d_in[0];
  const float* ln1_w    = (const float*)d_in[1];
  const float* ln1_b    = (const float*)d_in[2];
  const float* qkv_w    = (const float*)d_in[3];
  const float* qkv_b    = (const float*)d_in[4];
  const float* qkv_dw_w = (const float*)d_in[5];
  const float* qkv_dw_b = (const float*)d_in[6];
  const float* temp     = (const float*)d_in[7];
  const float* proj_w   = (const float*)d_in[8];
  const float* proj_b   = (const float*)d_in[9];
  const float* ln2_w    = (const float*)d_in[10];
  const float* ln2_b    = (const float*)d_in[11];
  const float* pin_w    = (const float*)d_in[12];
  const float* pin_b    = (const float*)d_in[13];
  const float* dw_w     = (const float*)d_in[14];
  const float* dw_b     = (const float*)d_in[15];
  const float* pout_w   = (const float*)d_in[16];
  const float* pout_b   = (const float*)d_in[17];
  float* out = (float*)d_out;
  char* ws = (char*)d_ws;

  u16* Wq   = (u16*)ws;                        // 640*192
  u16* Wpj  = Wq + 640 * 192;                  // 256*192
  u16* Wpi  = Wpj + 256 * 192;                 // 1024*192
  u16* Wpo  = Wpi + 1024 * 192;                // 256*512
  float* invn  = (float*)(Wpo + 256 * 512);    // 4*96
  float* attnm = invn + 384;                   // 9216
  float* part  = attnm + 9216;                 // 589824
  float* partN = part + 589824;                // 24576
  u16* yT   = (u16*)(partN + 24576);           // NB * HW * 192
  u16* bufA = yT + (i64)NB * HW * DIM;         // 1020*HW bf16 (qkv1/h1/attnoutT)
  u16* bufQ = bufA + (i64)H2 * HW;             // 576*HW bf16 (qkv post-dw / gatedT)
  u16* attnoutT = bufA;
  u16* gatedT = bufQ;
  size_t need = (size_t)((char*)(bufQ + (i64)OQKV * HW) - ws);
  if (ws_size < need) return;

  wconv_all<<<(499712 + 255) / 256, 256, 0, stream>>>(qkv_w, proj_w, pin_w, pout_w,
                                                      Wq, Wpj, Wpi, Wpo);
  ln_kernel<<<dim3(HW / 32, NB), 256, 0, stream>>>(x, ln1_w, ln1_b, yT);

  for (int b = 0; b < NB; ++b) {
    const float* xb = x + (i64)b * DIM * HW;
    float* outb = out + (i64)b * DIM * HW;
    u16* yTb = yT + (i64)b * HW * DIM;

    // ---- attention branch ----
    gemm_bf16<<<dim3(HW / 128, 640 / 128), 256, 0, stream>>>(Wq, qkv_b, yTb, nullptr, nullptr, bufA, OQKV, DIM);
    dwconv_bf16<<<dim3(OQKV / 64, 128), 256, 0, stream>>>(bufA, qkv_dw_w, qkv_dw_b, bufQ);
    attn_qk_kernel<<<dim3(NHEADS, NSPLIT), 256, 0, stream>>>(bufQ, part, partN);
    norm_reduce<<<1, 384, 0, stream>>>(partN, invn);
    attn_sm_kernel<<<dim3(NHEADS, CH), 64, 0, stream>>>(part, invn, temp, attnm);
    attn_v_kernel<<<dim3(NHEADS, HW / 256), 256, 0, stream>>>(bufQ, attnm, attnoutT);
    gemm_bf16<<<dim3(HW / 128, 256 / 128), 256, 0, stream>>>(Wpj, proj_b, attnoutT, xb, outb, nullptr, DIM, DIM);

    // ---- FFN branch ----
    ln_kernel<<<dim3(HW / 32, 1), 256, 0, stream>>>(outb, ln2_w, ln2_b, yTb);
    gemm_bf16<<<dim3(HW / 128, 1024 / 128), 256, 0, stream>>>(Wpi, pin_b, yTb, nullptr, nullptr, bufA, H2, DIM);
    dwgate_bf16<<<dim3(8, 128), 256, 0, stream>>>(bufA, dw_w, dw_b, gatedT);
    gemm_bf16<<<dim3(HW / 128, 256 / 128), 256, 0, stream>>>(Wpo, pout_b, gatedT, outb, outb, nullptr, DIM, 512);
  }
}

// Round 7
// 589.848 us; speedup vs baseline: 1.7886x; 1.3350x over previous
//
#include <hip/hip_runtime.h>
#include <math.h>

typedef long long i64;
typedef unsigned short u16;
typedef unsigned int u32;

#define HW 16384
#define DIM 192
#define NHEADS 4
#define CH 48
#define OQKV 576
#define HID 510
#define H2 1020
#define NB 4
#define NSPLIT 64

typedef __attribute__((ext_vector_type(8))) short short8v;
typedef __attribute__((ext_vector_type(4))) float float4v;

__device__ __forceinline__ u16 f2bf(float f) {
  union { float f; u32 u; } v; v.f = f;
  u32 r = v.u + 0x7FFF + ((v.u >> 16) & 1);
  return (u16)(r >> 16);
}
__device__ __forceinline__ float bflo(u32 w) {
  union { u32 u; float f; } v; v.u = w << 16; return v.f;
}
__device__ __forceinline__ float bfhi(u32 w) {
  union { u32 u; float f; } v; v.u = w & 0xFFFF0000u; return v.f;
}
__device__ __forceinline__ float bf1(u16 h) {
  union { u32 u; float f; } v; v.u = ((u32)h) << 16; return v.f;
}
__device__ __forceinline__ u32 pk(float a, float b) {
  return (u32)f2bf(a) | ((u32)f2bf(b) << 16);
}
__device__ __forceinline__ float gelu_f(float x) {
  float y = 0.7978845608f * (x + 0.044715f * x * x * x);
  float ay = fabsf(y);
  float e = __expf(-2.f * ay);
  float t = (1.f - e) / (1.f + e);
  t = (y < 0.f) ? -t : t;
  return 0.5f * x * (1.f + t);
}

#define GLL16(gp, lp) __builtin_amdgcn_global_load_lds( \
    (const __attribute__((address_space(1))) u32*)(gp), \
    (__attribute__((address_space(3))) u32*)(lp), 16, 0, 0)

// ---------------- LayerNorm over channels -> bf16 pixel-major [N,192] --------
// blockIdx.y = batch (x stride DIM*HW, yT stride HW*DIM)
__global__ __launch_bounds__(256) void ln_kernel(const float* __restrict__ x,
    const float* __restrict__ w, const float* __restrict__ b, u16* __restrict__ yT) {
  __shared__ float st[32][193];
  __shared__ float red[2][8][32];
  __shared__ float murs[2][32];
  const float* xb = x + (i64)blockIdx.y * DIM * HW;
  u16* yb = yT + (i64)blockIdx.y * (i64)HW * DIM;
  int tid = threadIdx.x;
  int g = tid >> 5, p = tid & 31;
  int pix0 = blockIdx.x * 32;
  float s = 0.f, ss = 0.f;
  #pragma unroll
  for (int i = 0; i < 24; ++i) {
    float t = xb[(i64)(g * 24 + i) * HW + pix0 + p];
    st[p][g * 24 + i] = t; s += t; ss += t * t;
  }
  red[0][g][p] = s; red[1][g][p] = ss;
  __syncthreads();
  if (tid < 32) {
    float S = 0.f, SS = 0.f;
    #pragma unroll
    for (int gg = 0; gg < 8; ++gg) { S += red[0][gg][tid]; SS += red[1][gg][tid]; }
    float mu = S * (1.f / DIM);
    float var = SS * (1.f / DIM) - mu * mu;
    murs[0][tid] = mu;
    murs[1][tid] = rsqrtf(var + 1e-5f);
  }
  __syncthreads();
  int px = tid >> 3, c0 = (tid & 7) * 24;
  float mu = murs[0][px], rs = murs[1][px];
  u16 ob[24];
  #pragma unroll
  for (int i = 0; i < 24; ++i) {
    ob[i] = f2bf((st[px][c0 + i] - mu) * rs * w[c0 + i] + b[c0 + i]);
  }
  u16* yp = yb + (i64)(pix0 + px) * DIM + c0;
  #pragma unroll
  for (int j = 0; j < 3; ++j) *(uint4*)(yp + j * 8) = *(const uint4*)&ob[j * 8];
}

// ---------------- all weights fp32 -> bf16 zero-padded, one launch -----------
__global__ __launch_bounds__(256) void wconv_all(const float* __restrict__ qkv_w,
    const float* __restrict__ proj_w, const float* __restrict__ pin_w,
    const float* __restrict__ pout_w, u16* __restrict__ Wq, u16* __restrict__ Wpj,
    u16* __restrict__ Wpi, u16* __restrict__ Wpo) {
  int idx = blockIdx.x * 256 + threadIdx.x;
  const float* src; u16* dst; int O, C, Kpad;
  if (idx < 122880)      { src = qkv_w;  dst = Wq;  O = OQKV; C = 192; Kpad = 192; }
  else if (idx < 172032) { idx -= 122880; src = proj_w; dst = Wpj; O = 192;  C = 192; Kpad = 192; }
  else if (idx < 368640) { idx -= 172032; src = pin_w;  dst = Wpi; O = H2;   C = 192; Kpad = 192; }
  else if (idx < 499712) { idx -= 368640; src = pout_w; dst = Wpo; O = 192;  C = HID; Kpad = 512; }
  else return;
  int r = idx / Kpad, c = idx - r * Kpad;
  dst[idx] = f2bf((r < O && c < C) ? src[(i64)r * C + c] : 0.f);
}

// ---------------- bf16 MFMA GEMM, batched via blockIdx.z ---------------------
__global__ __launch_bounds__(256) void gemm_bf16(const u16* __restrict__ A,
    const float* __restrict__ bias, const u16* __restrict__ B,
    const float* __restrict__ Res, float* __restrict__ Out,
    u16* __restrict__ OutB, int O, int K, i64 sB, i64 sOut, i64 sRes) {
  __shared__ __align__(16) u16 lds[2 * 128 * 64];
  int zb = blockIdx.z;
  B += (i64)zb * sB;
  if (Res) Res += (i64)zb * sRes;
  if (OutB) OutB += (i64)zb * sOut; else Out += (i64)zb * sOut;
  int tid = threadIdx.x;
  int lane = tid & 63, wave = tid >> 6;
  int wm = (wave >> 1) * 64, wn = (wave & 1) * 64;
  int obase = blockIdx.y * 128, nbase = blockIdx.x * 128;
  float4v acc[4][4];
  #pragma unroll
  for (int m = 0; m < 4; ++m)
    #pragma unroll
    for (int n = 0; n < 4; ++n) acc[m][n] = (float4v){0.f, 0.f, 0.f, 0.f};

  const u16* Abase = A + (i64)obase * K;
  const u16* Bbase = B + (i64)nbase * K;
  char* ldsA = (char*)&lds[0];
  char* ldsB = (char*)&lds[8192];
  int srow = wave * 8 + (lane >> 3);
  int sj = lane & 7;

  for (int k0 = 0; k0 < K; k0 += 64) {
    #pragma unroll
    for (int iss = 0; iss < 4; ++iss) {
      int r = iss * 32 + srow;
      int kb = sj ^ (r & 7);
      GLL16(Abase + (i64)r * K + k0 + kb * 8, ldsA + iss * 4096 + wave * 1024);
      GLL16(Bbase + (i64)r * K + k0 + kb * 8, ldsB + iss * 4096 + wave * 1024);
    }
    __syncthreads();
    #pragma unroll
    for (int kk = 0; kk < 2; ++kk) {
      short8v af[4], bfr[4];
      #pragma unroll
      for (int m = 0; m < 4; ++m) {
        int r = wm + m * 16 + (lane & 15);
        int kb = kk * 4 + (lane >> 4);
        af[m] = *(const short8v*)(ldsA + r * 128 + ((kb ^ (r & 7)) << 4));
      }
      #pragma unroll
      for (int n = 0; n < 4; ++n) {
        int r = wn + n * 16 + (lane & 15);
        int kb = kk * 4 + (lane >> 4);
        bfr[n] = *(const short8v*)(ldsB + r * 128 + ((kb ^ (r & 7)) << 4));
      }
      #pragma unroll
      for (int m = 0; m < 4; ++m)
        #pragma unroll
        for (int n = 0; n < 4; ++n)
          acc[m][n] = __builtin_amdgcn_mfma_f32_16x16x32_bf16(af[m], bfr[n], acc[m][n], 0, 0, 0);
    }
    __syncthreads();
  }

  int rowq = lane >> 4, coln = lane & 15;
  #pragma unroll
  for (int m = 0; m < 4; ++m) {
    #pragma unroll
    for (int reg = 0; reg < 4; ++reg) {
      int o = obase + wm + m * 16 + rowq * 4 + reg;
      if (o >= O) continue;
      float bv = bias[o];
      #pragma unroll
      for (int n = 0; n < 4; ++n) {
        int nn = nbase + wn + n * 16 + coln;
        float v = acc[m][n][reg] + bv;
        if (OutB) {
          OutB[(i64)o * HW + nn] = f2bf(v);
        } else {
          if (Res) v += Res[(i64)o * HW + nn];
          Out[(i64)o * HW + nn] = v;
        }
      }
    }
  }
}

// ---------------- depthwise 3x3, bf16 [C,HW] -> bf16 [C,HW], z = batch -------
__global__ __launch_bounds__(256) void dwconv_bf16(const u16* __restrict__ in,
    const float* __restrict__ w9, const float* __restrict__ bs,
    u16* __restrict__ out) {
  in  += (i64)blockIdx.z * OQKV * HW;
  out += (i64)blockIdx.z * OQKV * HW;
  int q = threadIdx.x & 31;
  int grp = threadIdx.x >> 5;
  int y = blockIdx.y;
  int c0 = blockIdx.x * 64 + grp * 8;
  int xb = q * 4;
  #pragma unroll
  for (int i = 0; i < 8; ++i) {
    int c = c0 + i;
    const float* wp = w9 + c * 9;
    float bv = bs[c];
    float a0 = bv, a1 = bv, a2 = bv, a3 = bv;
    const u16* chan = in + (i64)c * HW;
    #pragma unroll
    for (int dy = -1; dy <= 1; ++dy) {
      int yy = y + dy;
      if (yy < 0 || yy >= 128) continue;
      uint4 raw = *(const uint4*)(chan + yy * 128 + xb - 2);
      float f1 = bfhi(raw.x);
      float f2 = bflo(raw.y), f3 = bfhi(raw.y);
      float f4 = bflo(raw.z), f5 = bfhi(raw.z);
      float f6 = bflo(raw.w);
      if (q == 0) f1 = 0.f;
      if (q == 31) f6 = 0.f;
      float wa = wp[(dy + 1) * 3 + 0], wb = wp[(dy + 1) * 3 + 1], wc = wp[(dy + 1) * 3 + 2];
      a0 += wa * f1 + wb * f2 + wc * f3;
      a1 += wa * f2 + wb * f3 + wc * f4;
      a2 += wa * f3 + wb * f4 + wc * f5;
      a3 += wa * f4 + wb * f5 + wc * f6;
    }
    ushort4 o;
    o.x = f2bf(a0); o.y = f2bf(a1); o.z = f2bf(a2); o.w = f2bf(a3);
    *(ushort4*)(out + (i64)c * HW + y * 128 + xb) = o;
  }
}

// ---------------- q @ k^T split-K partials + sq-norm partials, z = batch -----
__global__ __launch_bounds__(256) void attn_qk_kernel(const u16* __restrict__ qkv,
    float* __restrict__ part, float* __restrict__ partN) {
  qkv   += (i64)blockIdx.z * OQKV * HW;
  part  += (i64)blockIdx.z * 589824;
  partN += (i64)blockIdx.z * 24576;
  __shared__ float qs[48][128];
  __shared__ float ks[48][128];
  int h = blockIdx.x, sp = blockIdx.y;
  int n0 = sp * (HW / NSPLIT);
  const u16* qb = qkv + (i64)(h * CH) * HW + n0;
  const u16* kb = qkv + (i64)(DIM + h * CH) * HW + n0;
  int tid = threadIdx.x;
  int c0 = (tid >> 4) * 3, d0 = (tid & 15) * 3;
  bool isq = (tid & 15) == 0;
  bool isk = (tid >> 4) == 0;
  float acc[3][3] = {};
  float qn[3] = {}, kn[3] = {};
  for (int nn = 0; nn < 256; nn += 128) {
    for (int l = tid; l < 48 * 16; l += 256) {
      int r = l >> 4, j = (l & 15) * 8;
      uint4 rq = *(const uint4*)(qb + (i64)r * HW + nn + j);
      uint4 rk = *(const uint4*)(kb + (i64)r * HW + nn + j);
      qs[r][j + 0] = bflo(rq.x); qs[r][j + 1] = bfhi(rq.x);
      qs[r][j + 2] = bflo(rq.y); qs[r][j + 3] = bfhi(rq.y);
      qs[r][j + 4] = bflo(rq.z); qs[r][j + 5] = bfhi(rq.z);
      qs[r][j + 6] = bflo(rq.w); qs[r][j + 7] = bfhi(rq.w);
      ks[r][j + 0] = bflo(rk.x); ks[r][j + 1] = bfhi(rk.x);
      ks[r][j + 2] = bflo(rk.y); ks[r][j + 3] = bfhi(rk.y);
      ks[r][j + 4] = bflo(rk.z); ks[r][j + 5] = bfhi(rk.z);
      ks[r][j + 6] = bflo(rk.w); ks[r][j + 7] = bfhi(rk.w);
    }
    __syncthreads();
    #pragma unroll 2
    for (int j = 0; j < 128; j += 4) {
      float qv[3][4], kv[3][4];
      #pragma unroll
      for (int i = 0; i < 3; ++i) {
        float4 t = *(const float4*)&qs[c0 + i][j];
        qv[i][0] = t.x; qv[i][1] = t.y; qv[i][2] = t.z; qv[i][3] = t.w;
        float4 u = *(const float4*)&ks[d0 + i][j];
        kv[i][0] = u.x; kv[i][1] = u.y; kv[i][2] = u.z; kv[i][3] = u.w;
      }
      #pragma unroll
      for (int i = 0; i < 3; ++i)
        #pragma unroll
        for (int jj = 0; jj < 3; ++jj)
          #pragma unroll
          for (int e = 0; e < 4; ++e)
            acc[i][jj] += qv[i][e] * kv[jj][e];
      if (isq) {
        #pragma unroll
        for (int i = 0; i < 3; ++i)
          #pragma unroll
          for (int e = 0; e < 4; ++e) qn[i] += qv[i][e] * qv[i][e];
      }
      if (isk) {
        #pragma unroll
        for (int i = 0; i < 3; ++i)
          #pragma unroll
          for (int e = 0; e < 4; ++e) kn[i] += kv[i][e] * kv[i][e];
      }
    }
    __syncthreads();
  }
  float* pp = part + ((i64)(h * NSPLIT) + sp) * 2304;
  #pragma unroll
  for (int i = 0; i < 3; ++i)
    #pragma unroll
    for (int jj = 0; jj < 3; ++jj)
      pp[(c0 + i) * 48 + d0 + jj] = acc[i][jj];
  float* pn = partN + ((i64)(h * NSPLIT) + sp) * 96;
  if (isq) {
    #pragma unroll
    for (int i = 0; i < 3; ++i) pn[c0 + i] = qn[i];
  }
  if (isk) {
    #pragma unroll
    for (int i = 0; i < 3; ++i) pn[48 + d0 + i] = kn[i];
  }
}

// ---- fused norm-reduce + scale + softmax; grid (NHEADS, CH, nbat), 64 thr ---
__global__ __launch_bounds__(64) void attn_sm3(const float* __restrict__ part,
    const float* __restrict__ partN, const float* __restrict__ temp,
    float* __restrict__ attn) {
  part  += (i64)blockIdx.z * 589824;
  partN += (i64)blockIdx.z * 24576;
  attn  += (i64)blockIdx.z * 9216;
  int h = blockIdx.x, c = blockIdx.y;
  int d = threadIdx.x;
  const float* pN = partN + (i64)h * NSPLIT * 96;
  // q-norm for channel c: lane d reduces split d
  float sq = pN[d * 96 + c];
  #pragma unroll
  for (int mask = 32; mask; mask >>= 1) sq += __shfl_xor(sq, mask);
  float invq = 1.f / fmaxf(sqrtf(sq), 1e-12f);
  float logit = -1e30f;
  if (d < CH) {
    float sk = 0.f, s = 0.f;
    for (int sp = 0; sp < NSPLIT; ++sp) {
      sk += pN[sp * 96 + 48 + d];
      s += part[((i64)(h * NSPLIT) + sp) * 2304 + c * 48 + d];
    }
    float invk = 1.f / fmaxf(sqrtf(sk), 1e-12f);
    logit = s * invq * invk * temp[h];
  }
  float m = logit;
  #pragma unroll
  for (int mask = 32; mask; mask >>= 1) m = fmaxf(m, __shfl_xor(m, mask));
  float e = (d < CH) ? expf(logit - m) : 0.f;
  float ssum = e;
  #pragma unroll
  for (int mask = 32; mask; mask >>= 1) ssum += __shfl_xor(ssum, mask);
  if (d < CH) attn[(i64)h * 2304 + c * 48 + d] = e / ssum;
}

// ---------------- out = attn @ v; LDS-staged coalesced writes; z = batch -----
__global__ __launch_bounds__(256) void attn_v_kernel(const u16* __restrict__ qkv,
    const float* __restrict__ attnm, u16* __restrict__ outT) {
  qkv   += (i64)blockIdx.z * OQKV * HW;
  attnm += (i64)blockIdx.z * 9216;
  outT  += (i64)blockIdx.z * (i64)HW * DIM;
  __shared__ float as[CH * CH];
  __shared__ u16 st[256 * 52];
  int h = blockIdx.x, tile = blockIdx.y;
  int tid = threadIdx.x;
  for (int l = tid; l < CH * CH; l += 256) as[l] = attnm[(i64)h * 2304 + l];
  __syncthreads();
  int n = tile * 256 + tid;
  const u16* vb = qkv + (i64)(2 * DIM + h * CH) * HW + n;
  float vreg[CH];
  #pragma unroll
  for (int d = 0; d < CH; ++d) vreg[d] = bf1(vb[(i64)d * HW]);
  u32* strow = (u32*)st + tid * 26;
  #pragma unroll 2
  for (int c = 0; c < CH; c += 4) {
    float a0 = 0.f, a1 = 0.f, a2 = 0.f, a3 = 0.f;
    const float* r0 = &as[(c + 0) * CH];
    const float* r1 = &as[(c + 1) * CH];
    const float* r2 = &as[(c + 2) * CH];
    const float* r3 = &as[(c + 3) * CH];
    #pragma unroll
    for (int d = 0; d < CH; ++d) {
      float vv = vreg[d];
      a0 += r0[d] * vv; a1 += r1[d] * vv; a2 += r2[d] * vv; a3 += r3[d] * vv;
    }
    strow[(c >> 1) + 0] = pk(a0, a1);
    strow[(c >> 1) + 1] = pk(a2, a3);
  }
  __syncthreads();
  const uint2* sv = (const uint2*)st;
  u16* ob = outT + (i64)(tile * 256) * DIM + h * CH;
  #pragma unroll
  for (int k = 0; k < 12; ++k) {
    int idx = k * 256 + tid;
    int px = idx / 12, pc = idx - px * 12;
    *(uint2*)(ob + (i64)px * DIM + pc * 4) = sv[px * 13 + pc];
  }
}

// ---------------- fused FFN dw3x3 + GELU gate -> bf16 [N,512]; z = batch -----
__global__ __launch_bounds__(256) void dwgate_bf16(const u16* __restrict__ h1,
    const float* __restrict__ w9, const float* __restrict__ bs,
    u16* __restrict__ og) {
  h1 += (i64)blockIdx.z * H2 * HW;
  og += (i64)blockIdx.z * (i64)HW * 512;
  __shared__ u32 st[128 * 33];
  int q = threadIdx.x & 31;
  int grp = threadIdx.x >> 5;
  int y = blockIdx.y;
  int c0 = blockIdx.x * 64 + grp * 8;
  int xb = q * 4;
  float res[4][8];
  #pragma unroll
  for (int i = 0; i < 8; ++i) {
    int c = c0 + i;
    bool valid = (c < HID);
    float b1 = valid ? bs[c] : 0.f;
    float b2 = valid ? bs[c + HID] : 0.f;
    float a0 = b1, a1 = b1, a2 = b1, a3 = b1;
    float g0 = b2, g1 = b2, g2 = b2, g3 = b2;
    if (valid) {
      const float* wp1 = w9 + c * 9;
      const float* wp2 = w9 + (i64)(c + HID) * 9;
      const u16* ch1 = h1 + (i64)c * HW;
      const u16* ch2 = h1 + (i64)(c + HID) * HW;
      #pragma unroll
      for (int dy = -1; dy <= 1; ++dy) {
        int yy = y + dy;
        if (yy < 0 || yy >= 128) continue;
        {
          uint4 raw = *(const uint4*)(ch1 + yy * 128 + xb - 2);
          float f1 = bfhi(raw.x);
          float f2 = bflo(raw.y), f3 = bfhi(raw.y);
          float f4 = bflo(raw.z), f5 = bfhi(raw.z);
          float f6 = bflo(raw.w);
          if (q == 0) f1 = 0.f;
          if (q == 31) f6 = 0.f;
          float wa = wp1[(dy + 1) * 3 + 0], wb = wp1[(dy + 1) * 3 + 1], wc = wp1[(dy + 1) * 3 + 2];
          a0 += wa * f1 + wb * f2 + wc * f3;
          a1 += wa * f2 + wb * f3 + wc * f4;
          a2 += wa * f3 + wb * f4 + wc * f5;
          a3 += wa * f4 + wb * f5 + wc * f6;
        }
        {
          uint4 raw = *(const uint4*)(ch2 + yy * 128 + xb - 2);
          float f1 = bfhi(raw.x);
          float f2 = bflo(raw.y), f3 = bfhi(raw.y);
          float f4 = bflo(raw.z), f5 = bfhi(raw.z);
          float f6 = bflo(raw.w);
          if (q == 0) f1 = 0.f;
          if (q == 31) f6 = 0.f;
          float wa = wp2[(dy + 1) * 3 + 0], wb = wp2[(dy + 1) * 3 + 1], wc = wp2[(dy + 1) * 3 + 2];
          g0 += wa * f1 + wb * f2 + wc * f3;
          g1 += wa * f2 + wb * f3 + wc * f4;
          g2 += wa * f3 + wb * f4 + wc * f5;
          g3 += wa * f4 + wb * f5 + wc * f6;
        }
      }
    }
    res[0][i] = valid ? gelu_f(a0) * g0 : 0.f;
    res[1][i] = valid ? gelu_f(a1) * g1 : 0.f;
    res[2][i] = valid ? gelu_f(a2) * g2 : 0.f;
    res[3][i] = valid ? gelu_f(a3) * g3 : 0.f;
  }
  #pragma unroll
  for (int j = 0; j < 4; ++j) {
    int px = xb + j;
    u32* row = st + px * 33 + grp * 4;
    row[0] = pk(res[j][0], res[j][1]);
    row[1] = pk(res[j][2], res[j][3]);
    row[2] = pk(res[j][4], res[j][5]);
    row[3] = pk(res[j][6], res[j][7]);
  }
  __syncthreads();
  u32* og32 = (u32*)og;
  int tid = threadIdx.x;
  #pragma unroll
  for (int k = 0; k < 16; ++k) {
    int idx = k * 256 + tid;
    int px = idx >> 5, dwi = idx & 31;
    og32[(i64)(y * 128 + px) * 256 + blockIdx.x * 32 + dwi] = st[px * 33 + dwi];
  }
}

extern "C" void kernel_launch(void* const* d_in, const int* in_sizes, int n_in,
                              void* d_out, int out_size, void* d_ws, size_t ws_size,
                              hipStream_t stream) {
  const float* x        = (const float*)d_in[0];
  const float* ln1_w    = (const float*)d_in[1];
  const float* ln1_b    = (const float*)d_in[2];
  const float* qkv_w    = (const float*)d_in[3];
  const float* qkv_b    = (const float*)d_in[4];
  const float* qkv_dw_w = (const float*)d_in[5];
  const float* qkv_dw_b = (const float*)d_in[6];
  const float* temp     = (const float*)d_in[7];
  const float* proj_w   = (const float*)d_in[8];
  const float* proj_b   = (const float*)d_in[9];
  const float* ln2_w    = (const float*)d_in[10];
  const float* ln2_b    = (const float*)d_in[11];
  const float* pin_w    = (const float*)d_in[12];
  const float* pin_b    = (const float*)d_in[13];
  const float* dw_w     = (const float*)d_in[14];
  const float* dw_b     = (const float*)d_in[15];
  const float* pout_w   = (const float*)d_in[16];
  const float* pout_b   = (const float*)d_in[17];
  float* out = (float*)d_out;
  char* ws = (char*)d_ws;

  // fixed-size regions
  u16* Wq   = (u16*)ws;                        // 640*192
  u16* Wpj  = Wq + 640 * 192;                  // 256*192
  u16* Wpi  = Wpj + 256 * 192;                 // 1024*192
  u16* Wpo  = Wpi + 1024 * 192;                // 256*512
  u16* yT   = Wpo + 256 * 512;                 // NB * HW * 192 (always all 4)
  char* dyn = (char*)(yT + (i64)NB * HW * DIM);

  // per-nbat regions: attnm, part, partN, bufA, bufQ
  auto layout = [&](int nb, float*& attnm, float*& part, float*& partN,
                    u16*& bufA, u16*& bufQ) -> size_t {
    char* p = dyn;
    attnm = (float*)p; p += (i64)nb * 9216 * 4;
    part  = (float*)p; p += (i64)nb * 589824 * 4;
    partN = (float*)p; p += (i64)nb * 24576 * 4;
    bufA  = (u16*)p;   p += (i64)nb * H2 * HW * 2;
    bufQ  = (u16*)p;   p += (i64)nb * OQKV * HW * 2;
    return (size_t)(p - ws);
  };

  float *attnm, *part, *partN; u16 *bufA, *bufQ;
  int nbat = 4;
  if (layout(4, attnm, part, partN, bufA, bufQ) > ws_size) {
    nbat = 1;
    if (layout(1, attnm, part, partN, bufA, bufQ) > ws_size) return;
  }

  wconv_all<<<(499712 + 255) / 256, 256, 0, stream>>>(qkv_w, proj_w, pin_w, pout_w,
                                                      Wq, Wpj, Wpi, Wpo);
  ln_kernel<<<dim3(HW / 32, NB), 256, 0, stream>>>(x, ln1_w, ln1_b, yT);

  for (int b0 = 0; b0 < NB; b0 += nbat) {
    const float* xb = x + (i64)b0 * DIM * HW;
    float* outb = out + (i64)b0 * DIM * HW;
    u16* yTb = yT + (i64)b0 * HW * DIM;
    u16* attnoutT = bufA;                 // stride HW*DIM, alias bufA region
    u16* gatedT = bufQ;                   // stride HW*512, alias bufQ region

    // ---- attention branch ----
    gemm_bf16<<<dim3(HW / 128, 5, nbat), 256, 0, stream>>>(
        Wq, qkv_b, yTb, nullptr, nullptr, bufA, OQKV, DIM,
        (i64)HW * DIM, (i64)OQKV * HW, 0);
    dwconv_bf16<<<dim3(OQKV / 64, 128, nbat), 256, 0, stream>>>(bufA, qkv_dw_w, qkv_dw_b, bufQ);
    attn_qk_kernel<<<dim3(NHEADS, NSPLIT, nbat), 256, 0, stream>>>(bufQ, part, partN);
    attn_sm3<<<dim3(NHEADS, CH, nbat), 64, 0, stream>>>(part, partN, temp, attnm);
    attn_v_kernel<<<dim3(NHEADS, HW / 256, nbat), 256, 0, stream>>>(bufQ, attnm, attnoutT);
    gemm_bf16<<<dim3(HW / 128, 2, nbat), 256, 0, stream>>>(
        Wpj, proj_b, attnoutT, xb, outb, nullptr, DIM, DIM,
        (i64)HW * DIM, (i64)DIM * HW, (i64)DIM * HW);

    // ---- FFN branch ----
    ln_kernel<<<dim3(HW / 32, nbat), 256, 0, stream>>>(outb, ln2_w, ln2_b, yTb);
    gemm_bf16<<<dim3(HW / 128, 8, nbat), 256, 0, stream>>>(
        Wpi, pin_b, yTb, nullptr, nullptr, bufA, H2, DIM,
        (i64)HW * DIM, (i64)H2 * HW, 0);
    dwgate_bf16<<<dim3(8, 128, nbat), 256, 0, stream>>>(bufA, dw_w, dw_b, gatedT);
    gemm_bf16<<<dim3(HW / 128, 2, nbat), 256, 0, stream>>>(
        Wpo, pout_b, gatedT, outb, outb, nullptr, DIM, 512,
        (i64)HW * 512, (i64)DIM * HW, (i64)DIM * HW);
  }
}

// Round 8
// 519.612 us; speedup vs baseline: 2.0304x; 1.1352x over previous
//
#include <hip/hip_runtime.h>
#include <math.h>

typedef long long i64;
typedef unsigned short u16;
typedef unsigned int u32;

#define HW 16384
#define DIM 192
#define NHEADS 4
#define CH 48
#define OQKV 576
#define HID 510
#define H2 1020
#define NB 4
#define NSPLIT 64
#define QKPAD 132   // LDS row stride (floats): 132%32=4 -> 16-way conflict becomes 2-way

typedef __attribute__((ext_vector_type(8))) short short8v;
typedef __attribute__((ext_vector_type(4))) float float4v;

__device__ __forceinline__ u16 f2bf(float f) {
  union { float f; u32 u; } v; v.f = f;
  u32 r = v.u + 0x7FFF + ((v.u >> 16) & 1);
  return (u16)(r >> 16);
}
__device__ __forceinline__ float bflo(u32 w) {
  union { u32 u; float f; } v; v.u = w << 16; return v.f;
}
__device__ __forceinline__ float bfhi(u32 w) {
  union { u32 u; float f; } v; v.u = w & 0xFFFF0000u; return v.f;
}
__device__ __forceinline__ float bf1(u16 h) {
  union { u32 u; float f; } v; v.u = ((u32)h) << 16; return v.f;
}
__device__ __forceinline__ u32 pk(float a, float b) {
  return (u32)f2bf(a) | ((u32)f2bf(b) << 16);
}
__device__ __forceinline__ float gelu_f(float x) {
  float y = 0.7978845608f * (x + 0.044715f * x * x * x);
  float ay = fabsf(y);
  float e = __expf(-2.f * ay);
  float t = (1.f - e) / (1.f + e);
  t = (y < 0.f) ? -t : t;
  return 0.5f * x * (1.f + t);
}

#define GLL16(gp, lp) __builtin_amdgcn_global_load_lds( \
    (const __attribute__((address_space(1))) u32*)(gp), \
    (__attribute__((address_space(3))) u32*)(lp), 16, 0, 0)

// ---------------- LayerNorm over channels -> bf16 pixel-major [N,192] --------
__global__ __launch_bounds__(256) void ln_kernel(const float* __restrict__ x,
    const float* __restrict__ w, const float* __restrict__ b, u16* __restrict__ yT) {
  __shared__ float st[32][193];
  __shared__ float red[2][8][32];
  __shared__ float murs[2][32];
  const float* xb = x + (i64)blockIdx.y * DIM * HW;
  u16* yb = yT + (i64)blockIdx.y * (i64)HW * DIM;
  int tid = threadIdx.x;
  int g = tid >> 5, p = tid & 31;
  int pix0 = blockIdx.x * 32;
  float s = 0.f, ss = 0.f;
  #pragma unroll
  for (int i = 0; i < 24; ++i) {
    float t = xb[(i64)(g * 24 + i) * HW + pix0 + p];
    st[p][g * 24 + i] = t; s += t; ss += t * t;
  }
  red[0][g][p] = s; red[1][g][p] = ss;
  __syncthreads();
  if (tid < 32) {
    float S = 0.f, SS = 0.f;
    #pragma unroll
    for (int gg = 0; gg < 8; ++gg) { S += red[0][gg][tid]; SS += red[1][gg][tid]; }
    float mu = S * (1.f / DIM);
    float var = SS * (1.f / DIM) - mu * mu;
    murs[0][tid] = mu;
    murs[1][tid] = rsqrtf(var + 1e-5f);
  }
  __syncthreads();
  int px = tid >> 3, c0 = (tid & 7) * 24;
  float mu = murs[0][px], rs = murs[1][px];
  u16 ob[24];
  #pragma unroll
  for (int i = 0; i < 24; ++i) {
    ob[i] = f2bf((st[px][c0 + i] - mu) * rs * w[c0 + i] + b[c0 + i]);
  }
  u16* yp = yb + (i64)(pix0 + px) * DIM + c0;
  #pragma unroll
  for (int j = 0; j < 3; ++j) *(uint4*)(yp + j * 8) = *(const uint4*)&ob[j * 8];
}

// ---------------- all weights fp32 -> bf16 zero-padded, one launch -----------
__global__ __launch_bounds__(256) void wconv_all(const float* __restrict__ qkv_w,
    const float* __restrict__ proj_w, const float* __restrict__ pin_w,
    const float* __restrict__ pout_w, u16* __restrict__ Wq, u16* __restrict__ Wpj,
    u16* __restrict__ Wpi, u16* __restrict__ Wpo) {
  int idx = blockIdx.x * 256 + threadIdx.x;
  const float* src; u16* dst; int O, C, Kpad;
  if (idx < 122880)      { src = qkv_w;  dst = Wq;  O = OQKV; C = 192; Kpad = 192; }
  else if (idx < 172032) { idx -= 122880; src = proj_w; dst = Wpj; O = 192;  C = 192; Kpad = 192; }
  else if (idx < 368640) { idx -= 172032; src = pin_w;  dst = Wpi; O = H2;   C = 192; Kpad = 192; }
  else if (idx < 499712) { idx -= 368640; src = pout_w; dst = Wpo; O = 192;  C = HID; Kpad = 512; }
  else return;
  int r = idx / Kpad, c = idx - r * Kpad;
  dst[idx] = f2bf((r < O && c < C) ? src[(i64)r * C + c] : 0.f);
}

// ---------------- bf16 MFMA GEMM, batched via blockIdx.z ---------------------
__global__ __launch_bounds__(256) void gemm_bf16(const u16* __restrict__ A,
    const float* __restrict__ bias, const u16* __restrict__ B,
    const float* __restrict__ Res, float* __restrict__ Out,
    u16* __restrict__ OutB, int O, int K, i64 sB, i64 sOut, i64 sRes) {
  __shared__ __align__(16) u16 lds[2 * 128 * 64];
  int zb = blockIdx.z;
  B += (i64)zb * sB;
  if (Res) Res += (i64)zb * sRes;
  if (OutB) OutB += (i64)zb * sOut; else Out += (i64)zb * sOut;
  int tid = threadIdx.x;
  int lane = tid & 63, wave = tid >> 6;
  int wm = (wave >> 1) * 64, wn = (wave & 1) * 64;
  int obase = blockIdx.y * 128, nbase = blockIdx.x * 128;
  float4v acc[4][4];
  #pragma unroll
  for (int m = 0; m < 4; ++m)
    #pragma unroll
    for (int n = 0; n < 4; ++n) acc[m][n] = (float4v){0.f, 0.f, 0.f, 0.f};

  const u16* Abase = A + (i64)obase * K;
  const u16* Bbase = B + (i64)nbase * K;
  char* ldsA = (char*)&lds[0];
  char* ldsB = (char*)&lds[8192];
  int srow = wave * 8 + (lane >> 3);
  int sj = lane & 7;

  for (int k0 = 0; k0 < K; k0 += 64) {
    #pragma unroll
    for (int iss = 0; iss < 4; ++iss) {
      int r = iss * 32 + srow;
      int kb = sj ^ (r & 7);
      GLL16(Abase + (i64)r * K + k0 + kb * 8, ldsA + iss * 4096 + wave * 1024);
      GLL16(Bbase + (i64)r * K + k0 + kb * 8, ldsB + iss * 4096 + wave * 1024);
    }
    __syncthreads();
    #pragma unroll
    for (int kk = 0; kk < 2; ++kk) {
      short8v af[4], bfr[4];
      #pragma unroll
      for (int m = 0; m < 4; ++m) {
        int r = wm + m * 16 + (lane & 15);
        int kb = kk * 4 + (lane >> 4);
        af[m] = *(const short8v*)(ldsA + r * 128 + ((kb ^ (r & 7)) << 4));
      }
      #pragma unroll
      for (int n = 0; n < 4; ++n) {
        int r = wn + n * 16 + (lane & 15);
        int kb = kk * 4 + (lane >> 4);
        bfr[n] = *(const short8v*)(ldsB + r * 128 + ((kb ^ (r & 7)) << 4));
      }
      #pragma unroll
      for (int m = 0; m < 4; ++m)
        #pragma unroll
        for (int n = 0; n < 4; ++n)
          acc[m][n] = __builtin_amdgcn_mfma_f32_16x16x32_bf16(af[m], bfr[n], acc[m][n], 0, 0, 0);
    }
    __syncthreads();
  }

  int rowq = lane >> 4, coln = lane & 15;
  #pragma unroll
  for (int m = 0; m < 4; ++m) {
    #pragma unroll
    for (int reg = 0; reg < 4; ++reg) {
      int o = obase + wm + m * 16 + rowq * 4 + reg;
      if (o >= O) continue;
      float bv = bias[o];
      #pragma unroll
      for (int n = 0; n < 4; ++n) {
        int nn = nbase + wn + n * 16 + coln;
        float v = acc[m][n][reg] + bv;
        if (OutB) {
          OutB[(i64)o * HW + nn] = f2bf(v);
        } else {
          if (Res) v += Res[(i64)o * HW + nn];
          Out[(i64)o * HW + nn] = v;
        }
      }
    }
  }
}

// ---------------- depthwise 3x3, bf16 [C,HW] -> bf16 [C,HW], z = batch -------
__global__ __launch_bounds__(256) void dwconv_bf16(const u16* __restrict__ in,
    const float* __restrict__ w9, const float* __restrict__ bs,
    u16* __restrict__ out) {
  in  += (i64)blockIdx.z * OQKV * HW;
  out += (i64)blockIdx.z * OQKV * HW;
  int q = threadIdx.x & 31;
  int grp = threadIdx.x >> 5;
  int y = blockIdx.y;
  int c0 = blockIdx.x * 64 + grp * 8;
  int xb = q * 4;
  #pragma unroll
  for (int i = 0; i < 8; ++i) {
    int c = c0 + i;
    const float* wp = w9 + c * 9;
    float bv = bs[c];
    float a0 = bv, a1 = bv, a2 = bv, a3 = bv;
    const u16* chan = in + (i64)c * HW;
    #pragma unroll
    for (int dy = -1; dy <= 1; ++dy) {
      int yy = y + dy;
      if (yy < 0 || yy >= 128) continue;
      uint4 raw = *(const uint4*)(chan + yy * 128 + xb - 2);
      float f1 = bfhi(raw.x);
      float f2 = bflo(raw.y), f3 = bfhi(raw.y);
      float f4 = bflo(raw.z), f5 = bfhi(raw.z);
      float f6 = bflo(raw.w);
      if (q == 0) f1 = 0.f;
      if (q == 31) f6 = 0.f;
      float wa = wp[(dy + 1) * 3 + 0], wb = wp[(dy + 1) * 3 + 1], wc = wp[(dy + 1) * 3 + 2];
      a0 += wa * f1 + wb * f2 + wc * f3;
      a1 += wa * f2 + wb * f3 + wc * f4;
      a2 += wa * f3 + wb * f4 + wc * f5;
      a3 += wa * f4 + wb * f5 + wc * f6;
    }
    ushort4 o;
    o.x = f2bf(a0); o.y = f2bf(a1); o.z = f2bf(a2); o.w = f2bf(a3);
    *(ushort4*)(out + (i64)c * HW + y * 128 + xb) = o;
  }
}

// ---------------- q @ k^T split-K partials + sq-norm partials, z = batch -----
__global__ __launch_bounds__(256) void attn_qk_kernel(const u16* __restrict__ qkv,
    float* __restrict__ part, float* __restrict__ partN) {
  qkv   += (i64)blockIdx.z * OQKV * HW;
  part  += (i64)blockIdx.z * 589824;
  partN += (i64)blockIdx.z * 24576;
  __shared__ float qs[48][QKPAD];
  __shared__ float ks[48][QKPAD];
  int h = blockIdx.x, sp = blockIdx.y;
  int n0 = sp * (HW / NSPLIT);
  const u16* qb = qkv + (i64)(h * CH) * HW + n0;
  const u16* kb = qkv + (i64)(DIM + h * CH) * HW + n0;
  int tid = threadIdx.x;
  int c0 = (tid >> 4) * 3, d0 = (tid & 15) * 3;
  bool isq = (tid & 15) == 0;
  bool isk = (tid >> 4) == 0;
  float acc[3][3] = {};
  float qn[3] = {}, kn[3] = {};
  for (int nn = 0; nn < 256; nn += 128) {
    for (int l = tid; l < 48 * 16; l += 256) {
      int r = l >> 4, j = (l & 15) * 8;
      uint4 rq = *(const uint4*)(qb + (i64)r * HW + nn + j);
      uint4 rk = *(const uint4*)(kb + (i64)r * HW + nn + j);
      qs[r][j + 0] = bflo(rq.x); qs[r][j + 1] = bfhi(rq.x);
      qs[r][j + 2] = bflo(rq.y); qs[r][j + 3] = bfhi(rq.y);
      qs[r][j + 4] = bflo(rq.z); qs[r][j + 5] = bfhi(rq.z);
      qs[r][j + 6] = bflo(rq.w); qs[r][j + 7] = bfhi(rq.w);
      ks[r][j + 0] = bflo(rk.x); ks[r][j + 1] = bfhi(rk.x);
      ks[r][j + 2] = bflo(rk.y); ks[r][j + 3] = bfhi(rk.y);
      ks[r][j + 4] = bflo(rk.z); ks[r][j + 5] = bfhi(rk.z);
      ks[r][j + 6] = bflo(rk.w); ks[r][j + 7] = bfhi(rk.w);
    }
    __syncthreads();
    #pragma unroll 2
    for (int j = 0; j < 128; j += 4) {
      float qv[3][4], kv[3][4];
      #pragma unroll
      for (int i = 0; i < 3; ++i) {
        float4 t = *(const float4*)&qs[c0 + i][j];
        qv[i][0] = t.x; qv[i][1] = t.y; qv[i][2] = t.z; qv[i][3] = t.w;
        float4 u = *(const float4*)&ks[d0 + i][j];
        kv[i][0] = u.x; kv[i][1] = u.y; kv[i][2] = u.z; kv[i][3] = u.w;
      }
      #pragma unroll
      for (int i = 0; i < 3; ++i)
        #pragma unroll
        for (int jj = 0; jj < 3; ++jj)
          #pragma unroll
          for (int e = 0; e < 4; ++e)
            acc[i][jj] += qv[i][e] * kv[jj][e];
      if (isq) {
        #pragma unroll
        for (int i = 0; i < 3; ++i)
          #pragma unroll
          for (int e = 0; e < 4; ++e) qn[i] += qv[i][e] * qv[i][e];
      }
      if (isk) {
        #pragma unroll
        for (int i = 0; i < 3; ++i)
          #pragma unroll
          for (int e = 0; e < 4; ++e) kn[i] += kv[i][e] * kv[i][e];
      }
    }
    __syncthreads();
  }
  float* pp = part + ((i64)(h * NSPLIT) + sp) * 2304;
  #pragma unroll
  for (int i = 0; i < 3; ++i)
    #pragma unroll
    for (int jj = 0; jj < 3; ++jj)
      pp[(c0 + i) * 48 + d0 + jj] = acc[i][jj];
  float* pn = partN + ((i64)(h * NSPLIT) + sp) * 96;
  if (isq) {
    #pragma unroll
    for (int i = 0; i < 3; ++i) pn[c0 + i] = qn[i];
  }
  if (isk) {
    #pragma unroll
    for (int i = 0; i < 3; ++i) pn[48 + d0 + i] = kn[i];
  }
}

// ---- fused norm-reduce + scale + softmax; grid (NHEADS, CH, nbat), 64 thr ---
__global__ __launch_bounds__(64) void attn_sm3(const float* __restrict__ part,
    const float* __restrict__ partN, const float* __restrict__ temp,
    float* __restrict__ attn) {
  part  += (i64)blockIdx.z * 589824;
  partN += (i64)blockIdx.z * 24576;
  attn  += (i64)blockIdx.z * 9216;
  int h = blockIdx.x, c = blockIdx.y;
  int d = threadIdx.x;
  const float* pN = partN + (i64)h * NSPLIT * 96;
  float sq = pN[d * 96 + c];
  #pragma unroll
  for (int mask = 32; mask; mask >>= 1) sq += __shfl_xor(sq, mask);
  float invq = 1.f / fmaxf(sqrtf(sq), 1e-12f);
  float logit = -1e30f;
  if (d < CH) {
    float sk = 0.f, s = 0.f;
    for (int sp = 0; sp < NSPLIT; ++sp) {
      sk += pN[sp * 96 + 48 + d];
      s += part[((i64)(h * NSPLIT) + sp) * 2304 + c * 48 + d];
    }
    float invk = 1.f / fmaxf(sqrtf(sk), 1e-12f);
    logit = s * invq * invk * temp[h];
  }
  float m = logit;
  #pragma unroll
  for (int mask = 32; mask; mask >>= 1) m = fmaxf(m, __shfl_xor(m, mask));
  float e = (d < CH) ? expf(logit - m) : 0.f;
  float ssum = e;
  #pragma unroll
  for (int mask = 32; mask; mask >>= 1) ssum += __shfl_xor(ssum, mask);
  if (d < CH) attn[(i64)h * 2304 + c * 48 + d] = e / ssum;
}

// ---------------- out = attn @ v; LDS-staged coalesced writes; z = batch -----
__global__ __launch_bounds__(256) void attn_v_kernel(const u16* __restrict__ qkv,
    const float* __restrict__ attnm, u16* __restrict__ outT) {
  qkv   += (i64)blockIdx.z * OQKV * HW;
  attnm += (i64)blockIdx.z * 9216;
  outT  += (i64)blockIdx.z * (i64)HW * DIM;
  __shared__ float as[CH * CH];
  __shared__ u16 st[256 * 52];
  int h = blockIdx.x, tile = blockIdx.y;
  int tid = threadIdx.x;
  for (int l = tid; l < CH * CH; l += 256) as[l] = attnm[(i64)h * 2304 + l];
  __syncthreads();
  int n = tile * 256 + tid;
  const u16* vb = qkv + (i64)(2 * DIM + h * CH) * HW + n;
  float vreg[CH];
  #pragma unroll
  for (int d = 0; d < CH; ++d) vreg[d] = bf1(vb[(i64)d * HW]);
  u32* strow = (u32*)st + tid * 26;
  #pragma unroll 2
  for (int c = 0; c < CH; c += 4) {
    float a0 = 0.f, a1 = 0.f, a2 = 0.f, a3 = 0.f;
    const float* r0 = &as[(c + 0) * CH];
    const float* r1 = &as[(c + 1) * CH];
    const float* r2 = &as[(c + 2) * CH];
    const float* r3 = &as[(c + 3) * CH];
    #pragma unroll
    for (int d = 0; d < CH; ++d) {
      float vv = vreg[d];
      a0 += r0[d] * vv; a1 += r1[d] * vv; a2 += r2[d] * vv; a3 += r3[d] * vv;
    }
    strow[(c >> 1) + 0] = pk(a0, a1);
    strow[(c >> 1) + 1] = pk(a2, a3);
  }
  __syncthreads();
  const uint2* sv = (const uint2*)st;
  u16* ob = outT + (i64)(tile * 256) * DIM + h * CH;
  #pragma unroll
  for (int k = 0; k < 12; ++k) {
    int idx = k * 256 + tid;
    int px = idx / 12, pc = idx - px * 12;
    *(uint2*)(ob + (i64)px * DIM + pc * 4) = sv[px * 13 + pc];
  }
}

// ---------------- fused FFN dw3x3 + GELU gate -> bf16 [N,512]; z = batch -----
__global__ __launch_bounds__(256) void dwgate_bf16(const u16* __restrict__ h1,
    const float* __restrict__ w9, const float* __restrict__ bs,
    u16* __restrict__ og) {
  h1 += (i64)blockIdx.z * H2 * HW;
  og += (i64)blockIdx.z * (i64)HW * 512;
  __shared__ u32 st[128 * 33];
  int q = threadIdx.x & 31;
  int grp = threadIdx.x >> 5;
  int y = blockIdx.y;
  int c0 = blockIdx.x * 64 + grp * 8;
  int xb = q * 4;
  float res[4][8];
  #pragma unroll
  for (int i = 0; i < 8; ++i) {
    int c = c0 + i;
    bool valid = (c < HID);
    float b1 = valid ? bs[c] : 0.f;
    float b2 = valid ? bs[c + HID] : 0.f;
    float a0 = b1, a1 = b1, a2 = b1, a3 = b1;
    float g0 = b2, g1 = b2, g2 = b2, g3 = b2;
    if (valid) {
      const float* wp1 = w9 + c * 9;
      const float* wp2 = w9 + (i64)(c + HID) * 9;
      const u16* ch1 = h1 + (i64)c * HW;
      const u16* ch2 = h1 + (i64)(c + HID) * HW;
      #pragma unroll
      for (int dy = -1; dy <= 1; ++dy) {
        int yy = y + dy;
        if (yy < 0 || yy >= 128) continue;
        {
          uint4 raw = *(const uint4*)(ch1 + yy * 128 + xb - 2);
          float f1 = bfhi(raw.x);
          float f2 = bflo(raw.y), f3 = bfhi(raw.y);
          float f4 = bflo(raw.z), f5 = bfhi(raw.z);
          float f6 = bflo(raw.w);
          if (q == 0) f1 = 0.f;
          if (q == 31) f6 = 0.f;
          float wa = wp1[(dy + 1) * 3 + 0], wb = wp1[(dy + 1) * 3 + 1], wc = wp1[(dy + 1) * 3 + 2];
          a0 += wa * f1 + wb * f2 + wc * f3;
          a1 += wa * f2 + wb * f3 + wc * f4;
          a2 += wa * f3 + wb * f4 + wc * f5;
          a3 += wa * f4 + wb * f5 + wc * f6;
        }
        {
          uint4 raw = *(const uint4*)(ch2 + yy * 128 + xb - 2);
          float f1 = bfhi(raw.x);
          float f2 = bflo(raw.y), f3 = bfhi(raw.y);
          float f4 = bflo(raw.z), f5 = bfhi(raw.z);
          float f6 = bflo(raw.w);
          if (q == 0) f1 = 0.f;
          if (q == 31) f6 = 0.f;
          float wa = wp2[(dy + 1) * 3 + 0], wb = wp2[(dy + 1) * 3 + 1], wc = wp2[(dy + 1) * 3 + 2];
          g0 += wa * f1 + wb * f2 + wc * f3;
          g1 += wa * f2 + wb * f3 + wc * f4;
          g2 += wa * f3 + wb * f4 + wc * f5;
          g3 += wa * f4 + wb * f5 + wc * f6;
        }
      }
    }
    res[0][i] = valid ? gelu_f(a0) * g0 : 0.f;
    res[1][i] = valid ? gelu_f(a1) * g1 : 0.f;
    res[2][i] = valid ? gelu_f(a2) * g2 : 0.f;
    res[3][i] = valid ? gelu_f(a3) * g3 : 0.f;
  }
  #pragma unroll
  for (int j = 0; j < 4; ++j) {
    int px = xb + j;
    u32* row = st + px * 33 + grp * 4;
    row[0] = pk(res[j][0], res[j][1]);
    row[1] = pk(res[j][2], res[j][3]);
    row[2] = pk(res[j][4], res[j][5]);
    row[3] = pk(res[j][6], res[j][7]);
  }
  __syncthreads();
  u32* og32 = (u32*)og;
  int tid = threadIdx.x;
  #pragma unroll
  for (int k = 0; k < 16; ++k) {
    int idx = k * 256 + tid;
    int px = idx >> 5, dwi = idx & 31;
    og32[(i64)(y * 128 + px) * 256 + blockIdx.x * 32 + dwi] = st[px * 33 + dwi];
  }
}

extern "C" void kernel_launch(void* const* d_in, const int* in_sizes, int n_in,
                              void* d_out, int out_size, void* d_ws, size_t ws_size,
                              hipStream_t stream) {
  const float* x        = (const float*)d_in[0];
  const float* ln1_w    = (const float*)d_in[1];
  const float* ln1_b    = (const float*)d_in[2];
  const float* qkv_w    = (const float*)d_in[3];
  const float* qkv_b    = (const float*)d_in[4];
  const float* qkv_dw_w = (const float*)d_in[5];
  const float* qkv_dw_b = (const float*)d_in[6];
  const float* temp     = (const float*)d_in[7];
  const float* proj_w   = (const float*)d_in[8];
  const float* proj_b   = (const float*)d_in[9];
  const float* ln2_w    = (const float*)d_in[10];
  const float* ln2_b    = (const float*)d_in[11];
  const float* pin_w    = (const float*)d_in[12];
  const float* pin_b    = (const float*)d_in[13];
  const float* dw_w     = (const float*)d_in[14];
  const float* dw_b     = (const float*)d_in[15];
  const float* pout_w   = (const float*)d_in[16];
  const float* pout_b   = (const float*)d_in[17];
  float* out = (float*)d_out;
  char* ws = (char*)d_ws;

  u16* Wq   = (u16*)ws;
  u16* Wpj  = Wq + 640 * 192;
  u16* Wpi  = Wpj + 256 * 192;
  u16* Wpo  = Wpi + 1024 * 192;
  u16* yT   = Wpo + 256 * 512;
  char* dyn = (char*)(yT + (i64)NB * HW * DIM);

  auto layout = [&](int nb, float*& attnm, float*& part, float*& partN,
                    u16*& bufA, u16*& bufQ) -> size_t {
    char* p = dyn;
    attnm = (float*)p; p += (i64)nb * 9216 * 4;
    part  = (float*)p; p += (i64)nb * 589824 * 4;
    partN = (float*)p; p += (i64)nb * 24576 * 4;
    bufA  = (u16*)p;   p += (i64)nb * H2 * HW * 2;
    bufQ  = (u16*)p;   p += (i64)nb * OQKV * HW * 2;
    return (size_t)(p - ws);
  };

  float *attnm, *part, *partN; u16 *bufA, *bufQ;
  int nbat = 4;
  if (layout(4, attnm, part, partN, bufA, bufQ) > ws_size) {
    nbat = 1;
    if (layout(1, attnm, part, partN, bufA, bufQ) > ws_size) return;
  }

  wconv_all<<<(499712 + 255) / 256, 256, 0, stream>>>(qkv_w, proj_w, pin_w, pout_w,
                                                      Wq, Wpj, Wpi, Wpo);
  ln_kernel<<<dim3(HW / 32, NB), 256, 0, stream>>>(x, ln1_w, ln1_b, yT);

  for (int b0 = 0; b0 < NB; b0 += nbat) {
    const float* xb = x + (i64)b0 * DIM * HW;
    float* outb = out + (i64)b0 * DIM * HW;
    u16* yTb = yT + (i64)b0 * HW * DIM;
    u16* attnoutT = bufA;
    u16* gatedT = bufQ;

    // ---- attention branch ----
    gemm_bf16<<<dim3(HW / 128, 5, nbat), 256, 0, stream>>>(
        Wq, qkv_b, yTb, nullptr, nullptr, bufA, OQKV, DIM,
        (i64)HW * DIM, (i64)OQKV * HW, 0);
    dwconv_bf16<<<dim3(OQKV / 64, 128, nbat), 256, 0, stream>>>(bufA, qkv_dw_w, qkv_dw_b, bufQ);
    attn_qk_kernel<<<dim3(NHEADS, NSPLIT, nbat), 256, 0, stream>>>(bufQ, part, partN);
    attn_sm3<<<dim3(NHEADS, CH, nbat), 64, 0, stream>>>(part, partN, temp, attnm);
    attn_v_kernel<<<dim3(NHEADS, HW / 256, nbat), 256, 0, stream>>>(bufQ, attnm, attnoutT);
    gemm_bf16<<<dim3(HW / 128, 2, nbat), 256, 0, stream>>>(
        Wpj, proj_b, attnoutT, xb, outb, nullptr, DIM, DIM,
        (i64)HW * DIM, (i64)DIM * HW, (i64)DIM * HW);

    // ---- FFN branch ----
    ln_kernel<<<dim3(HW / 32, nbat), 256, 0, stream>>>(outb, ln2_w, ln2_b, yTb);
    gemm_bf16<<<dim3(HW / 128, 8, nbat), 256, 0, stream>>>(
        Wpi, pin_b, yTb, nullptr, nullptr, bufA, H2, DIM,
        (i64)HW * DIM, (i64)H2 * HW, 0);
    dwgate_bf16<<<dim3(8, 128, nbat), 256, 0, stream>>>(bufA, dw_w, dw_b, gatedT);
    gemm_bf16<<<dim3(HW / 128, 2, nbat), 256, 0, stream>>>(
        Wpo, pout_b, gatedT, outb, outb, nullptr, DIM, 512,
        (i64)HW * 512, (i64)DIM * HW, (i64)DIM * HW);
  }
}